// Round 2
// baseline (1137.308 us; speedup 1.0000x reference)
//
#include <hip/hip_runtime.h>

// ---------------------------------------------------------------------------
// DeformableTransformer encoder layer, MI355X (gfx950).
// Inputs/outputs are FLOAT32 (reference dtype). Internals use bf16 MFMA GEMMs
// with f32 accumulation; intermediates stored bf16 where precision allows.
// ---------------------------------------------------------------------------

typedef __bf16 bf16_t;
typedef __bf16 bf16x8 __attribute__((ext_vector_type(8)));
typedef __bf16 bf16x4 __attribute__((ext_vector_type(4)));
typedef float  f32x4  __attribute__((ext_vector_type(4)));

#define M_ROWS 17000   // B*S
#define S_LEN  8500
#define C_DIM  512

// ---------------------------------------------------------------- helpers
__device__ inline bf16x8 load8_as_bf16(const bf16_t* p) {
    return *(const bf16x8*)p;
}
__device__ inline bf16x8 load8_as_bf16(const float* p) {
    float4 f0 = *(const float4*)p;
    float4 f1 = *(const float4*)(p + 4);
    bf16x8 v;
    v[0] = (bf16_t)f0.x; v[1] = (bf16_t)f0.y; v[2] = (bf16_t)f0.z; v[3] = (bf16_t)f0.w;
    v[4] = (bf16_t)f1.x; v[5] = (bf16_t)f1.y; v[6] = (bf16_t)f1.z; v[7] = (bf16_t)f1.w;
    return v;
}
__device__ inline void store_c(float* p, float v)  { *p = v; }
__device__ inline void store_c(bf16_t* p, float v) { *p = (bf16_t)v; }

__device__ inline float4 load4f(const float* p)  { return *(const float4*)p; }
__device__ inline float4 load4f(const bf16_t* p) {
    bf16x4 v = *(const bf16x4*)p;
    return make_float4((float)v[0], (float)v[1], (float)v[2], (float)v[3]);
}

// ---------------------------------------------------------------- q = src+pos
// f32 + f32 -> bf16, 4 elems/thread
__global__ __launch_bounds__(256)
void add_q_kernel(const float* __restrict__ a, const float* __restrict__ b,
                  bf16_t* __restrict__ q, int n4) {
    int i = blockIdx.x * 256 + threadIdx.x;
    if (i >= n4) return;
    float4 av = *(const float4*)(a + (size_t)i * 4);
    float4 bv = *(const float4*)(b + (size_t)i * 4);
    bf16x4 ov;
    ov[0] = (bf16_t)(av.x + bv.x);
    ov[1] = (bf16_t)(av.y + bv.y);
    ov[2] = (bf16_t)(av.z + bv.z);
    ov[3] = (bf16_t)(av.w + bv.w);
    *(bf16x4*)(q + (size_t)i * 4) = ov;
}

// ---------------------------------------------------------------- GEMM
// C[M,N] = A[M,K] @ W[K,N] + bias, optional ReLU.
// 64x64 tile, BK=32, 4 waves (256 thr). MFMA f32_16x16x32_bf16.
// A-frag: lane holds A[m=lane&15][k=quad*8+j]; B-frag: B[k=quad*8+j][n=lane&15]
// D: col=lane&15, row=quad*4+reg.  (verified layouts, m89/m91/m120)
template<typename AT, typename WT, typename OT, bool RELU>
__global__ __launch_bounds__(256)
void gemm_kernel(const AT* __restrict__ A, const WT* __restrict__ W,
                 const float* __restrict__ bias, OT* __restrict__ Cout,
                 int M, int N, int K) {
    __shared__ bf16_t As[64][40];   // [m][k], stride 40 keeps 16B alignment
    __shared__ bf16_t Bs[64][40];   // [n][k] (transposed)

    const int tid  = threadIdx.x;
    const int wave = tid >> 6;
    const int lane = tid & 63;
    const int row0 = blockIdx.x * 64;
    const int col0 = blockIdx.y * 64;

    f32x4 acc[4];
    #pragma unroll
    for (int i = 0; i < 4; i++)
        #pragma unroll
        for (int j = 0; j < 4; j++) acc[i][j] = 0.f;

    const int am = tid >> 2;          // 0..63  (m within tile)
    const int ak = (tid & 3) * 8;     // 0,8,16,24
    const int bk = tid >> 3;          // 0..31  (k within chunk)
    const int bn = (tid & 7) * 8;     // 0..56

    const int quad = lane >> 4;
    const int lq   = lane & 15;

    for (int kk = 0; kk < K; kk += 32) {
        // ---- stage A tile 64x32
        {
            int grow = row0 + am;
            bf16x8 av;
            if (grow < M) {
                av = load8_as_bf16(A + (size_t)grow * K + kk + ak);
            } else {
                #pragma unroll
                for (int j = 0; j < 8; j++) av[j] = (bf16_t)0.f;
            }
            *(bf16x8*)&As[am][ak] = av;
        }
        // ---- stage B tile 32x64 (transpose into Bs[n][k])
        {
            bf16x8 bv = load8_as_bf16(W + (size_t)(kk + bk) * N + col0 + bn);
            #pragma unroll
            for (int j = 0; j < 8; j++) Bs[bn + j][bk] = bv[j];
        }
        __syncthreads();

        bf16x8 a = *(const bf16x8*)&As[wave * 16 + lq][quad * 8];
        #pragma unroll
        for (int nt = 0; nt < 4; nt++) {
            bf16x8 b = *(const bf16x8*)&Bs[nt * 16 + lq][quad * 8];
            acc[nt] = __builtin_amdgcn_mfma_f32_16x16x32_bf16(a, b, acc[nt], 0, 0, 0);
        }
        __syncthreads();
    }

    // ---- epilogue
    #pragma unroll
    for (int nt = 0; nt < 4; nt++) {
        int col = col0 + nt * 16 + lq;
        float bcol = bias[col];
        #pragma unroll
        for (int r = 0; r < 4; r++) {
            int row = row0 + wave * 16 + quad * 4 + r;
            if (row < M) {
                float v = acc[nt][r] + bcol;
                if (RELU) v = fmaxf(v, 0.f);
                store_c(Cout + (size_t)row * N + col, v);
            }
        }
    }
}

// ---------------------------------------------------------------- softmax16
__global__ __launch_bounds__(256)
void softmax16_kernel(float* __restrict__ x, int ngroups) {
    int i = blockIdx.x * 256 + threadIdx.x;
    if (i >= ngroups) return;
    float* p = x + (size_t)i * 16;
    float v[16];
    float4* p4 = (float4*)p;
    #pragma unroll
    for (int j = 0; j < 4; j++) {
        float4 t = p4[j];
        v[4*j+0] = t.x; v[4*j+1] = t.y; v[4*j+2] = t.z; v[4*j+3] = t.w;
    }
    float mx = v[0];
    #pragma unroll
    for (int j = 1; j < 16; j++) mx = fmaxf(mx, v[j]);
    float sm = 0.f;
    #pragma unroll
    for (int j = 0; j < 16; j++) { v[j] = __expf(v[j] - mx); sm += v[j]; }
    float inv = 1.f / sm;
    #pragma unroll
    for (int j = 0; j < 4; j++)
        p4[j] = make_float4(v[4*j]*inv, v[4*j+1]*inv, v[4*j+2]*inv, v[4*j+3]*inv);
}

// ---------------------------------------------------------------- sampling
// one wave per (b, s, head); lane = channel 0..63
__global__ __launch_bounds__(256)
void sample_kernel(const bf16_t* __restrict__ value, const float* __restrict__ off,
                   const float* __restrict__ attn, bf16_t* __restrict__ out) {
    int gw   = blockIdx.x * 4 + (threadIdx.x >> 6);
    int lane = threadIdx.x & 63;
    if (gw >= 2 * S_LEN * 8) return;
    int h  = gw & 7;
    int bs = gw >> 3;
    int b  = bs / S_LEN;
    int s  = bs - b * S_LEN;

    // reference point of this query (from its own level's grid)
    float rx, ry;
    if (s < 6400)      { int i = s;        float inv = 1.f/80.f; ry = ((i/80) + 0.5f)*inv; rx = ((i%80) + 0.5f)*inv; }
    else if (s < 8000) { int i = s - 6400; float inv = 1.f/40.f; ry = ((i/40) + 0.5f)*inv; rx = ((i%40) + 0.5f)*inv; }
    else if (s < 8400) { int i = s - 8000; float inv = 1.f/20.f; ry = ((i/20) + 0.5f)*inv; rx = ((i%20) + 0.5f)*inv; }
    else               { int i = s - 8400; float inv = 1.f/10.f; ry = ((i/10) + 0.5f)*inv; rx = ((i%10) + 0.5f)*inv; }

    const int WH[4]  = {80, 40, 20, 10};
    const int LST[4] = {0, 6400, 8000, 8400};

    // lanes 0..15 each own one (level,point); others duplicate harmlessly
    int lp = lane & 15;
    int ll = lp >> 2;
    size_t ob = ((size_t)bs * 8 + h) * 32 + lp * 2;
    float ox = off[ob], oy = off[ob + 1];
    float aw = attn[((size_t)bs * 8 + h) * 16 + lp];
    float invw = 1.f / (float)WH[ll];
    float lx = rx + ox * invw;
    float ly = ry + oy * invw;

    const bf16_t* vb = value + (size_t)b * S_LEN * 512 + h * 64 + lane;
    float acc = 0.f;
    #pragma unroll
    for (int j = 0; j < 16; j++) {
        float jx = __shfl(lx, j, 64);
        float jy = __shfl(ly, j, 64);
        float jw = __shfl(aw, j, 64);
        int l = j >> 2;
        int W = WH[l], H = WH[l], st = LST[l];
        float x = jx * (float)W - 0.5f;
        float y = jy * (float)H - 0.5f;
        float fx = floorf(x), fy = floorf(y);
        int x0 = (int)fx, y0 = (int)fy;
        float wx = x - fx, wy = y - fy;
        float w00 = (1.f - wx) * (1.f - wy);
        float w01 = wx * (1.f - wy);
        float w10 = (1.f - wx) * wy;
        float w11 = wx * wy;
        bool x0i = (x0 >= 0) && (x0 < W);
        bool x1i = (x0 + 1 >= 0) && (x0 + 1 < W);
        bool y0i = (y0 >= 0) && (y0 < H);
        bool y1i = (y0 + 1 >= 0) && (y0 + 1 < H);
        float v00 = 0.f, v01 = 0.f, v10 = 0.f, v11 = 0.f;
        if (x0i && y0i) v00 = (float)vb[(size_t)(st + y0 * W + x0) * 512];
        if (x1i && y0i) v01 = (float)vb[(size_t)(st + y0 * W + x0 + 1) * 512];
        if (x0i && y1i) v10 = (float)vb[(size_t)(st + (y0 + 1) * W + x0) * 512];
        if (x1i && y1i) v11 = (float)vb[(size_t)(st + (y0 + 1) * W + x0 + 1) * 512];
        acc += jw * (w00 * v00 + w01 * v01 + w10 * v10 + w11 * v11);
    }
    out[(size_t)bs * 512 + h * 64 + lane] = (bf16_t)acc;
}

// ---------------------------------------------------------------- LayerNorm
// out = LN(Xa + Xb) * g + b ; row of 512; one wave per row, 4 rows/block
template<typename INA, typename INB, typename OT>
__global__ __launch_bounds__(256)
void ln_kernel(const INA* __restrict__ Xa, const INB* __restrict__ Xb,
               const float* __restrict__ g, const float* __restrict__ be,
               OT* __restrict__ out, int M) {
    int wave = threadIdx.x >> 6;
    int lane = threadIdx.x & 63;
    int row = blockIdx.x * 4 + wave;
    if (row >= M) return;
    size_t base = (size_t)row * 512;
    float v[8];
    float s = 0.f, sq = 0.f;
    #pragma unroll
    for (int p = 0; p < 2; p++) {
        int idx = p * 256 + lane * 4;
        float4 a4 = load4f(Xa + base + idx);
        float4 b4 = load4f(Xb + base + idx);
        float t0 = a4.x + b4.x, t1 = a4.y + b4.y, t2 = a4.z + b4.z, t3 = a4.w + b4.w;
        v[p*4+0] = t0; v[p*4+1] = t1; v[p*4+2] = t2; v[p*4+3] = t3;
        s  += t0 + t1 + t2 + t3;
        sq += t0*t0 + t1*t1 + t2*t2 + t3*t3;
    }
    #pragma unroll
    for (int off = 32; off > 0; off >>= 1) {
        s  += __shfl_xor(s, off, 64);
        sq += __shfl_xor(sq, off, 64);
    }
    float mean = s * (1.f / 512.f);
    float var  = sq * (1.f / 512.f) - mean * mean;
    float rstd = rsqrtf(var + 1e-5f);
    #pragma unroll
    for (int p = 0; p < 2; p++) {
        int idx = p * 256 + lane * 4;
        #pragma unroll
        for (int j = 0; j < 4; j++) {
            int col = idx + j;
            float o = (v[p*4+j] - mean) * rstd * g[col] + be[col];
            store_c(out + base + col, o);
        }
    }
}

// ---------------------------------------------------------------- launch
extern "C" void kernel_launch(void* const* d_in, const int* in_sizes, int n_in,
                              void* d_out, int out_size, void* d_ws, size_t ws_size,
                              hipStream_t stream) {
    const float* src    = (const float*)d_in[0];
    const float* pos    = (const float*)d_in[1];
    const float* w_off  = (const float*)d_in[2];
    const float* b_off  = (const float*)d_in[3];
    const float* w_attn = (const float*)d_in[4];
    const float* b_attn = (const float*)d_in[5];
    const float* w_val  = (const float*)d_in[6];
    const float* b_val  = (const float*)d_in[7];
    const float* w_out  = (const float*)d_in[8];
    const float* b_out  = (const float*)d_in[9];
    const float* ln1_g  = (const float*)d_in[10];
    const float* ln1_b  = (const float*)d_in[11];
    const float* w1     = (const float*)d_in[12];
    const float* b1     = (const float*)d_in[13];
    const float* w2     = (const float*)d_in[14];
    const float* b2     = (const float*)d_in[15];
    const float* ln2_g  = (const float*)d_in[16];
    const float* ln2_b  = (const float*)d_in[17];

    const int M = M_ROWS;
    char* ws = (char*)d_ws;
    size_t o = 0;
    auto alloc = [&](size_t bytes) { size_t r = o; o += (bytes + 255) & ~(size_t)255; return r; };

    // live ranges allow aliasing: hidden over [sampled..offtmp], ffn_out over
    // [attntmp..attn_out). Peak ws ~113 MB.
    size_t off_q       = alloc((size_t)M * 512 * 2);   // bf16
    size_t off_value   = alloc((size_t)M * 512 * 2);   // bf16
    size_t off_sampled = alloc((size_t)M * 512 * 2);   // bf16
    size_t off_offtmp  = alloc((size_t)M * 256 * 4);   // f32
    size_t off_attntmp = alloc((size_t)M * 128 * 4);   // f32
    size_t off_attnout = alloc((size_t)M * 512 * 2);   // bf16
    size_t off_x       = alloc((size_t)M * 512 * 2);   // bf16

    bf16_t* q        = (bf16_t*)(ws + off_q);
    bf16_t* value    = (bf16_t*)(ws + off_value);
    bf16_t* sampled  = (bf16_t*)(ws + off_sampled);
    float*  offtmp   = (float*)(ws + off_offtmp);
    float*  attntmp  = (float*)(ws + off_attntmp);
    bf16_t* attn_out = (bf16_t*)(ws + off_attnout);
    bf16_t* x        = (bf16_t*)(ws + off_x);
    bf16_t* hidden   = (bf16_t*)(ws + off_sampled);   // alias: sampled+offtmp dead
    bf16_t* ffn_out  = (bf16_t*)(ws + off_attntmp);   // alias: attntmp+attn_out dead
    float*  outp     = (float*)d_out;

    const int MT = (M + 63) / 64;   // 266

    add_q_kernel<<<(M * 512 / 4 + 255) / 256, 256, 0, stream>>>(src, pos, q, M * 512 / 4);

    gemm_kernel<float,  float, bf16_t, false><<<dim3(MT, 8), 256, 0, stream>>>(src, w_val, b_val, value, M, 512, 512);
    gemm_kernel<bf16_t, float, float,  false><<<dim3(MT, 4), 256, 0, stream>>>(q, w_off, b_off, offtmp, M, 256, 512);
    gemm_kernel<bf16_t, float, float,  false><<<dim3(MT, 2), 256, 0, stream>>>(q, w_attn, b_attn, attntmp, M, 128, 512);

    softmax16_kernel<<<(M * 8 + 255) / 256, 256, 0, stream>>>(attntmp, M * 8);

    sample_kernel<<<(M * 8) / 4, 256, 0, stream>>>(value, offtmp, attntmp, sampled);

    gemm_kernel<bf16_t, float, bf16_t, false><<<dim3(MT, 8), 256, 0, stream>>>(sampled, w_out, b_out, attn_out, M, 512, 512);

    ln_kernel<float, bf16_t, bf16_t><<<(M + 3) / 4, 256, 0, stream>>>(src, attn_out, ln1_g, ln1_b, x, M);

    gemm_kernel<bf16_t, float, bf16_t, true ><<<dim3(MT, 16), 256, 0, stream>>>(x, w1, b1, hidden, M, 1024, 512);
    gemm_kernel<bf16_t, float, bf16_t, false><<<dim3(MT, 8), 256, 0, stream>>>(hidden, w2, b2, ffn_out, M, 512, 1024);

    ln_kernel<bf16_t, bf16_t, float><<<(M + 3) / 4, 256, 0, stream>>>(x, ffn_out, ln2_g, ln2_b, outp, M);
}

// Round 3
// 596.752 us; speedup vs baseline: 1.9058x; 1.9058x over previous
//
#include <hip/hip_runtime.h>

// ---------------------------------------------------------------------------
// DeformableTransformer encoder layer, MI355X (gfx950).
// Inputs/outputs are FLOAT32 (reference dtype). Internals use bf16 MFMA GEMMs
// with f32 accumulation; intermediates stored bf16 where precision allows.
// R2: sampling rewritten — lane = (point,corner) pair for weight/addr setup,
// 16B/lane vectorized value gathers (8 mem instrs/wave instead of 64).
// ---------------------------------------------------------------------------

typedef __bf16 bf16_t;
typedef __bf16 bf16x8 __attribute__((ext_vector_type(8)));
typedef __bf16 bf16x4 __attribute__((ext_vector_type(4)));
typedef float  f32x4  __attribute__((ext_vector_type(4)));

#define M_ROWS 17000   // B*S
#define S_LEN  8500
#define C_DIM  512

// ---------------------------------------------------------------- helpers
__device__ inline bf16x8 load8_as_bf16(const bf16_t* p) {
    return *(const bf16x8*)p;
}
__device__ inline bf16x8 load8_as_bf16(const float* p) {
    float4 f0 = *(const float4*)p;
    float4 f1 = *(const float4*)(p + 4);
    bf16x8 v;
    v[0] = (bf16_t)f0.x; v[1] = (bf16_t)f0.y; v[2] = (bf16_t)f0.z; v[3] = (bf16_t)f0.w;
    v[4] = (bf16_t)f1.x; v[5] = (bf16_t)f1.y; v[6] = (bf16_t)f1.z; v[7] = (bf16_t)f1.w;
    return v;
}
__device__ inline void store_c(float* p, float v)  { *p = v; }
__device__ inline void store_c(bf16_t* p, float v) { *p = (bf16_t)v; }

__device__ inline float4 load4f(const float* p)  { return *(const float4*)p; }
__device__ inline float4 load4f(const bf16_t* p) {
    bf16x4 v = *(const bf16x4*)p;
    return make_float4((float)v[0], (float)v[1], (float)v[2], (float)v[3]);
}

// ---------------------------------------------------------------- q = src+pos
__global__ __launch_bounds__(256)
void add_q_kernel(const float* __restrict__ a, const float* __restrict__ b,
                  bf16_t* __restrict__ q, int n4) {
    int i = blockIdx.x * 256 + threadIdx.x;
    if (i >= n4) return;
    float4 av = *(const float4*)(a + (size_t)i * 4);
    float4 bv = *(const float4*)(b + (size_t)i * 4);
    bf16x4 ov;
    ov[0] = (bf16_t)(av.x + bv.x);
    ov[1] = (bf16_t)(av.y + bv.y);
    ov[2] = (bf16_t)(av.z + bv.z);
    ov[3] = (bf16_t)(av.w + bv.w);
    *(bf16x4*)(q + (size_t)i * 4) = ov;
}

// ---------------------------------------------------------------- GEMM
// C[M,N] = A[M,K] @ W[K,N] + bias, optional ReLU.
// 64x64 tile, BK=32, 4 waves (256 thr). MFMA f32_16x16x32_bf16.
template<typename AT, typename WT, typename OT, bool RELU>
__global__ __launch_bounds__(256)
void gemm_kernel(const AT* __restrict__ A, const WT* __restrict__ W,
                 const float* __restrict__ bias, OT* __restrict__ Cout,
                 int M, int N, int K) {
    __shared__ bf16_t As[64][40];   // [m][k], stride 40 keeps 16B alignment
    __shared__ bf16_t Bs[64][40];   // [n][k] (transposed)

    const int tid  = threadIdx.x;
    const int wave = tid >> 6;
    const int lane = tid & 63;
    const int row0 = blockIdx.x * 64;
    const int col0 = blockIdx.y * 64;

    f32x4 acc[4];
    #pragma unroll
    for (int i = 0; i < 4; i++)
        #pragma unroll
        for (int j = 0; j < 4; j++) acc[i][j] = 0.f;

    const int am = tid >> 2;          // 0..63  (m within tile)
    const int ak = (tid & 3) * 8;     // 0,8,16,24
    const int bk = tid >> 3;          // 0..31  (k within chunk)
    const int bn = (tid & 7) * 8;     // 0..56

    const int quad = lane >> 4;
    const int lq   = lane & 15;

    for (int kk = 0; kk < K; kk += 32) {
        // ---- stage A tile 64x32
        {
            int grow = row0 + am;
            bf16x8 av;
            if (grow < M) {
                av = load8_as_bf16(A + (size_t)grow * K + kk + ak);
            } else {
                #pragma unroll
                for (int j = 0; j < 8; j++) av[j] = (bf16_t)0.f;
            }
            *(bf16x8*)&As[am][ak] = av;
        }
        // ---- stage B tile 32x64 (transpose into Bs[n][k])
        {
            bf16x8 bv = load8_as_bf16(W + (size_t)(kk + bk) * N + col0 + bn);
            #pragma unroll
            for (int j = 0; j < 8; j++) Bs[bn + j][bk] = bv[j];
        }
        __syncthreads();

        bf16x8 a = *(const bf16x8*)&As[wave * 16 + lq][quad * 8];
        #pragma unroll
        for (int nt = 0; nt < 4; nt++) {
            bf16x8 b = *(const bf16x8*)&Bs[nt * 16 + lq][quad * 8];
            acc[nt] = __builtin_amdgcn_mfma_f32_16x16x32_bf16(a, b, acc[nt], 0, 0, 0);
        }
        __syncthreads();
    }

    // ---- epilogue
    #pragma unroll
    for (int nt = 0; nt < 4; nt++) {
        int col = col0 + nt * 16 + lq;
        float bcol = bias[col];
        #pragma unroll
        for (int r = 0; r < 4; r++) {
            int row = row0 + wave * 16 + quad * 4 + r;
            if (row < M) {
                float v = acc[nt][r] + bcol;
                if (RELU) v = fmaxf(v, 0.f);
                store_c(Cout + (size_t)row * N + col, v);
            }
        }
    }
}

// ---------------------------------------------------------------- softmax16
__global__ __launch_bounds__(256)
void softmax16_kernel(float* __restrict__ x, int ngroups) {
    int i = blockIdx.x * 256 + threadIdx.x;
    if (i >= ngroups) return;
    float* p = x + (size_t)i * 16;
    float v[16];
    float4* p4 = (float4*)p;
    #pragma unroll
    for (int j = 0; j < 4; j++) {
        float4 t = p4[j];
        v[4*j+0] = t.x; v[4*j+1] = t.y; v[4*j+2] = t.z; v[4*j+3] = t.w;
    }
    float mx = v[0];
    #pragma unroll
    for (int j = 1; j < 16; j++) mx = fmaxf(mx, v[j]);
    float sm = 0.f;
    #pragma unroll
    for (int j = 0; j < 16; j++) { v[j] = __expf(v[j] - mx); sm += v[j]; }
    float inv = 1.f / sm;
    #pragma unroll
    for (int j = 0; j < 4; j++)
        p4[j] = make_float4(v[4*j]*inv, v[4*j+1]*inv, v[4*j+2]*inv, v[4*j+3]*inv);
}

// ---------------------------------------------------------------- sampling v2
// one wave per (b, s, head).
// Phase 1: lane i owns (point=i>>2, corner=i&3): computes folded weight
//          (attn * bilinear * valid) and clamped row address.
// Phase 2: 8 iters; lane-group g=lane>>3 handles pair it*8+g; its 8 lanes
//          load a contiguous bf16x8 (16B) of the 64-ch value row.
// Phase 3: xor-reduce over groups; lanes 0..7 store bf16x8.
__global__ __launch_bounds__(256)
void sample_kernel(const bf16_t* __restrict__ value, const float* __restrict__ off,
                   const float* __restrict__ attn, bf16_t* __restrict__ out) {
    int gw   = blockIdx.x * 4 + (threadIdx.x >> 6);
    int lane = threadIdx.x & 63;
    if (gw >= 2 * S_LEN * 8) return;
    int h  = gw & 7;
    int bs = gw >> 3;
    int b  = bs / S_LEN;
    int s  = bs - b * S_LEN;

    // reference point of this query (from its own level's grid)
    float rx, ry;
    if (s < 6400)      { int i = s;        float inv = 1.f/80.f; ry = ((i/80) + 0.5f)*inv; rx = ((i%80) + 0.5f)*inv; }
    else if (s < 8000) { int i = s - 6400; float inv = 1.f/40.f; ry = ((i/40) + 0.5f)*inv; rx = ((i%40) + 0.5f)*inv; }
    else if (s < 8400) { int i = s - 8000; float inv = 1.f/20.f; ry = ((i/20) + 0.5f)*inv; rx = ((i%20) + 0.5f)*inv; }
    else               { int i = s - 8400; float inv = 1.f/10.f; ry = ((i/10) + 0.5f)*inv; rx = ((i%10) + 0.5f)*inv; }

    const int WH[4]  = {80, 40, 20, 10};
    const int LST[4] = {0, 6400, 8000, 8400};

    // ---- phase 1: per-lane (point,corner) weight + address
    int pt = lane >> 2;          // 0..15
    int cn = lane & 3;           // 0..3 (bit0 = +x, bit1 = +y)
    int ll = pt >> 2;            // level
    int W  = WH[ll];
    float2 o2 = *(const float2*)(off + ((size_t)bs * 8 + h) * 32 + pt * 2);
    float  aw = attn[((size_t)bs * 8 + h) * 16 + pt];
    // x = (rx + ox/W)*W - 0.5 = rx*W + ox - 0.5   (levels are square: H == W)
    float x = fmaf(rx, (float)W, o2.x) - 0.5f;
    float y = fmaf(ry, (float)W, o2.y) - 0.5f;
    float fx = floorf(x), fy = floorf(y);
    float wx = x - fx,  wy = y - fy;
    int cx = (int)fx + (cn & 1);
    int cy = (int)fy + (cn >> 1);
    float wgt = aw * ((cn & 1) ? wx : 1.f - wx) * ((cn >> 1) ? wy : 1.f - wy);
    bool valid = (cx >= 0) && (cx < W) && (cy >= 0) && (cy < W);
    if (!valid) wgt = 0.f;
    int xc = min(max(cx, 0), W - 1);
    int yc = min(max(cy, 0), W - 1);
    int addr = LST[ll] + yc * W + xc;    // row index within [S] for this level

    // ---- phase 2: vectorized gather, 8 pairs per iteration
    const bf16_t* vb = value + ((size_t)b * S_LEN) * 512 + h * 64 + (lane & 7) * 8;
    int sub = lane >> 3;                 // 0..7
    float acc[8];
    #pragma unroll
    for (int j = 0; j < 8; j++) acc[j] = 0.f;
    #pragma unroll
    for (int it = 0; it < 8; it++) {
        int pair = it * 8 + sub;
        int   a = __shfl(addr, pair, 64);
        float w = __shfl(wgt,  pair, 64);
        bf16x8 v = *(const bf16x8*)(vb + (size_t)a * 512);
        #pragma unroll
        for (int j = 0; j < 8; j++) acc[j] += w * (float)v[j];
    }

    // ---- phase 3: reduce over the 8 pair-groups (lane bits 3..5)
    #pragma unroll
    for (int o = 8; o < 64; o <<= 1)
        #pragma unroll
        for (int j = 0; j < 8; j++) acc[j] += __shfl_xor(acc[j], o, 64);

    if (lane < 8) {
        bf16x8 ov;
        #pragma unroll
        for (int j = 0; j < 8; j++) ov[j] = (bf16_t)acc[j];
        *(bf16x8*)(out + (size_t)bs * 512 + h * 64 + lane * 8) = ov;
    }
}

// ---------------------------------------------------------------- LayerNorm
template<typename INA, typename INB, typename OT>
__global__ __launch_bounds__(256)
void ln_kernel(const INA* __restrict__ Xa, const INB* __restrict__ Xb,
               const float* __restrict__ g, const float* __restrict__ be,
               OT* __restrict__ out, int M) {
    int wave = threadIdx.x >> 6;
    int lane = threadIdx.x & 63;
    int row = blockIdx.x * 4 + wave;
    if (row >= M) return;
    size_t base = (size_t)row * 512;
    float v[8];
    float s = 0.f, sq = 0.f;
    #pragma unroll
    for (int p = 0; p < 2; p++) {
        int idx = p * 256 + lane * 4;
        float4 a4 = load4f(Xa + base + idx);
        float4 b4 = load4f(Xb + base + idx);
        float t0 = a4.x + b4.x, t1 = a4.y + b4.y, t2 = a4.z + b4.z, t3 = a4.w + b4.w;
        v[p*4+0] = t0; v[p*4+1] = t1; v[p*4+2] = t2; v[p*4+3] = t3;
        s  += t0 + t1 + t2 + t3;
        sq += t0*t0 + t1*t1 + t2*t2 + t3*t3;
    }
    #pragma unroll
    for (int off = 32; off > 0; off >>= 1) {
        s  += __shfl_xor(s, off, 64);
        sq += __shfl_xor(sq, off, 64);
    }
    float mean = s * (1.f / 512.f);
    float var  = sq * (1.f / 512.f) - mean * mean;
    float rstd = rsqrtf(var + 1e-5f);
    #pragma unroll
    for (int p = 0; p < 2; p++) {
        int idx = p * 256 + lane * 4;
        #pragma unroll
        for (int j = 0; j < 4; j++) {
            int col = idx + j;
            float o = (v[p*4+j] - mean) * rstd * g[col] + be[col];
            store_c(out + base + col, o);
        }
    }
}

// ---------------------------------------------------------------- launch
extern "C" void kernel_launch(void* const* d_in, const int* in_sizes, int n_in,
                              void* d_out, int out_size, void* d_ws, size_t ws_size,
                              hipStream_t stream) {
    const float* src    = (const float*)d_in[0];
    const float* pos    = (const float*)d_in[1];
    const float* w_off  = (const float*)d_in[2];
    const float* b_off  = (const float*)d_in[3];
    const float* w_attn = (const float*)d_in[4];
    const float* b_attn = (const float*)d_in[5];
    const float* w_val  = (const float*)d_in[6];
    const float* b_val  = (const float*)d_in[7];
    const float* w_out  = (const float*)d_in[8];
    const float* b_out  = (const float*)d_in[9];
    const float* ln1_g  = (const float*)d_in[10];
    const float* ln1_b  = (const float*)d_in[11];
    const float* w1     = (const float*)d_in[12];
    const float* b1     = (const float*)d_in[13];
    const float* w2     = (const float*)d_in[14];
    const float* b2     = (const float*)d_in[15];
    const float* ln2_g  = (const float*)d_in[16];
    const float* ln2_b  = (const float*)d_in[17];

    const int M = M_ROWS;
    char* ws = (char*)d_ws;
    size_t o = 0;
    auto alloc = [&](size_t bytes) { size_t r = o; o += (bytes + 255) & ~(size_t)255; return r; };

    size_t off_q       = alloc((size_t)M * 512 * 2);   // bf16
    size_t off_value   = alloc((size_t)M * 512 * 2);   // bf16
    size_t off_sampled = alloc((size_t)M * 512 * 2);   // bf16
    size_t off_offtmp  = alloc((size_t)M * 256 * 4);   // f32
    size_t off_attntmp = alloc((size_t)M * 128 * 4);   // f32
    size_t off_attnout = alloc((size_t)M * 512 * 2);   // bf16
    size_t off_x       = alloc((size_t)M * 512 * 2);   // bf16

    bf16_t* q        = (bf16_t*)(ws + off_q);
    bf16_t* value    = (bf16_t*)(ws + off_value);
    bf16_t* sampled  = (bf16_t*)(ws + off_sampled);
    float*  offtmp   = (float*)(ws + off_offtmp);
    float*  attntmp  = (float*)(ws + off_attntmp);
    bf16_t* attn_out = (bf16_t*)(ws + off_attnout);
    bf16_t* x        = (bf16_t*)(ws + off_x);
    bf16_t* hidden   = (bf16_t*)(ws + off_sampled);   // alias: sampled+offtmp dead
    bf16_t* ffn_out  = (bf16_t*)(ws + off_attntmp);   // alias: attntmp+attn_out dead
    float*  outp     = (float*)d_out;

    const int MT = (M + 63) / 64;   // 266

    add_q_kernel<<<(M * 512 / 4 + 255) / 256, 256, 0, stream>>>(src, pos, q, M * 512 / 4);

    gemm_kernel<float,  float, bf16_t, false><<<dim3(MT, 8), 256, 0, stream>>>(src, w_val, b_val, value, M, 512, 512);
    gemm_kernel<bf16_t, float, float,  false><<<dim3(MT, 4), 256, 0, stream>>>(q, w_off, b_off, offtmp, M, 256, 512);
    gemm_kernel<bf16_t, float, float,  false><<<dim3(MT, 2), 256, 0, stream>>>(q, w_attn, b_attn, attntmp, M, 128, 512);

    softmax16_kernel<<<(M * 8 + 255) / 256, 256, 0, stream>>>(attntmp, M * 8);

    sample_kernel<<<(M * 8) / 4, 256, 0, stream>>>(value, offtmp, attntmp, sampled);

    gemm_kernel<bf16_t, float, bf16_t, false><<<dim3(MT, 8), 256, 0, stream>>>(sampled, w_out, b_out, attn_out, M, 512, 512);

    ln_kernel<float, bf16_t, bf16_t><<<(M + 3) / 4, 256, 0, stream>>>(src, attn_out, ln1_g, ln1_b, x, M);

    gemm_kernel<bf16_t, float, bf16_t, true ><<<dim3(MT, 16), 256, 0, stream>>>(x, w1, b1, hidden, M, 1024, 512);
    gemm_kernel<bf16_t, float, bf16_t, false><<<dim3(MT, 8), 256, 0, stream>>>(hidden, w2, b2, ffn_out, M, 512, 1024);

    ln_kernel<bf16_t, bf16_t, float><<<(M + 3) / 4, 256, 0, stream>>>(x, ffn_out, ln2_g, ln2_b, outp, M);
}

// Round 5
// 450.308 us; speedup vs baseline: 2.5256x; 1.3252x over previous
//
#include <hip/hip_runtime.h>

// ---------------------------------------------------------------------------
// DeformableTransformer encoder layer, MI355X (gfx950).
// R3/R4: weights pre-transposed to bf16 W^T[N][K] once per launch, so GEMM B
// staging is contiguous ds_write_b128 (kills the 16-way LDS write conflicts
// of the in-kernel transpose). GEMM upgraded to 128x128 tile, BK=32,
// 4 waves x (4x4 16x16x32 MFMA). R4 fixes pragma-in-brace syntax error.
// ---------------------------------------------------------------------------

typedef __bf16 bf16_t;
typedef __bf16 bf16x8 __attribute__((ext_vector_type(8)));
typedef __bf16 bf16x4 __attribute__((ext_vector_type(4)));
typedef float  f32x4  __attribute__((ext_vector_type(4)));

#define M_ROWS 17000   // B*S
#define S_LEN  8500

// ---------------------------------------------------------------- helpers
__device__ inline void store_c(float* p, float v)  { *p = v; }
__device__ inline void store_c(bf16_t* p, float v) { *p = (bf16_t)v; }

__device__ inline float4 load4f(const float* p)  { return *(const float4*)p; }
__device__ inline float4 load4f(const bf16_t* p) {
    bf16x4 v = *(const bf16x4*)p;
    return make_float4((float)v[0], (float)v[1], (float)v[2], (float)v[3]);
}

__device__ inline bf16x8 zero8() {
    bf16x8 z;
    #pragma unroll
    for (int j = 0; j < 8; j++) z[j] = (bf16_t)0.f;
    return z;
}

// ---------------------------------------------------------------- weight T
// in: f32 [K][N] -> out: bf16 [N][K]; 32x32 LDS tiles, block 256 (32x8)
__global__ __launch_bounds__(256)
void transpose_kernel(const float* __restrict__ in, bf16_t* __restrict__ out,
                      int K, int N) {
    __shared__ float s[32][33];
    int tx = threadIdx.x & 31, ty = threadIdx.x >> 5;   // ty 0..7
    int k0 = blockIdx.x * 32, n0 = blockIdx.y * 32;
    #pragma unroll
    for (int i = 0; i < 4; i++)
        s[ty + 8 * i][tx] = in[(size_t)(k0 + ty + 8 * i) * N + n0 + tx];
    __syncthreads();
    #pragma unroll
    for (int i = 0; i < 4; i++)
        out[(size_t)(n0 + ty + 8 * i) * K + k0 + tx] = (bf16_t)s[tx][ty + 8 * i];
}

// ---------------------------------------------------------------- q = src+pos
// also emits bf16 copy of src (A-operand of the value GEMM)
__global__ __launch_bounds__(256)
void add_q_kernel(const float* __restrict__ a, const float* __restrict__ b,
                  bf16_t* __restrict__ q, bf16_t* __restrict__ src_bf, int n4) {
    int i = blockIdx.x * 256 + threadIdx.x;
    if (i >= n4) return;
    float4 av = *(const float4*)(a + (size_t)i * 4);
    float4 bv = *(const float4*)(b + (size_t)i * 4);
    bf16x4 sv, ov;
    sv[0] = (bf16_t)av.x; sv[1] = (bf16_t)av.y; sv[2] = (bf16_t)av.z; sv[3] = (bf16_t)av.w;
    ov[0] = (bf16_t)(av.x + bv.x);
    ov[1] = (bf16_t)(av.y + bv.y);
    ov[2] = (bf16_t)(av.z + bv.z);
    ov[3] = (bf16_t)(av.w + bv.w);
    *(bf16x4*)(q      + (size_t)i * 4) = ov;
    *(bf16x4*)(src_bf + (size_t)i * 4) = sv;
}

// ---------------------------------------------------------------- GEMM 128x128
// C[M,N] = A[M,K] @ Wt[N,K]^T + bias, optional ReLU. A,Wt bf16.
// BK=32, 4 waves; wave (wr,wc) computes 64x64 via 4x4 MFMA 16x16x32.
// Staging: thread stages 2 rows of A-tile and 2 rows of B-tile, 16B each
// (ds_write_b128, stride-40 rows -> uniform bank tiling, conflict-free).
template<typename OT, bool RELU>
__global__ __launch_bounds__(256)
void gemm128_kernel(const bf16_t* __restrict__ A, const bf16_t* __restrict__ Wt,
                    const float* __restrict__ bias, OT* __restrict__ Cout,
                    int M, int N, int K) {
    __shared__ bf16_t As[128][40];
    __shared__ bf16_t Bs[128][40];

    const int tid  = threadIdx.x;
    const int wave = tid >> 6;
    const int lane = tid & 63;
    const int quad = lane >> 4;
    const int lq   = lane & 15;
    const int wr   = (wave >> 1) * 64;   // wave row offset in tile
    const int wc   = (wave & 1) * 64;    // wave col offset in tile
    const int row0 = blockIdx.x * 128;
    const int col0 = blockIdx.y * 128;

    const int sr = tid >> 2;             // 0..63 staging row
    const int sc = (tid & 3) * 8;        // staging k-offset (elements)

    f32x4 acc[4][4];
    #pragma unroll
    for (int i = 0; i < 4; i++)
        #pragma unroll
        for (int j = 0; j < 4; j++)
            #pragma unroll
            for (int r = 0; r < 4; r++) acc[i][j][r] = 0.f;

    for (int kk = 0; kk < K; kk += 32) {
        // ---- stage A (128x32) and B (128x32)
        {
            int r0 = row0 + sr, r1 = row0 + sr + 64;
            bf16x8 a0 = zero8(), a1 = zero8();
            if (r0 < M) a0 = *(const bf16x8*)(A + (size_t)r0 * K + kk + sc);
            if (r1 < M) a1 = *(const bf16x8*)(A + (size_t)r1 * K + kk + sc);
            *(bf16x8*)&As[sr][sc]      = a0;
            *(bf16x8*)&As[sr + 64][sc] = a1;
            bf16x8 b0 = *(const bf16x8*)(Wt + (size_t)(col0 + sr) * K + kk + sc);
            bf16x8 b1 = *(const bf16x8*)(Wt + (size_t)(col0 + sr + 64) * K + kk + sc);
            *(bf16x8*)&Bs[sr][sc]      = b0;
            *(bf16x8*)&Bs[sr + 64][sc] = b1;
        }
        __syncthreads();

        bf16x8 af[4], bfr[4];
        #pragma unroll
        for (int i = 0; i < 4; i++)
            af[i] = *(const bf16x8*)&As[wr + i * 16 + lq][quad * 8];
        #pragma unroll
        for (int j = 0; j < 4; j++)
            bfr[j] = *(const bf16x8*)&Bs[wc + j * 16 + lq][quad * 8];
        #pragma unroll
        for (int i = 0; i < 4; i++)
            #pragma unroll
            for (int j = 0; j < 4; j++)
                acc[i][j] = __builtin_amdgcn_mfma_f32_16x16x32_bf16(af[i], bfr[j], acc[i][j], 0, 0, 0);
        __syncthreads();
    }

    // ---- epilogue: D col = lq (from B-frag), row = quad*4+r (from A-frag)
    #pragma unroll
    for (int j = 0; j < 4; j++) {
        int col = col0 + wc + j * 16 + lq;
        float bcol = bias[col];
        #pragma unroll
        for (int i = 0; i < 4; i++) {
            int rowb = row0 + wr + i * 16 + quad * 4;
            #pragma unroll
            for (int r = 0; r < 4; r++) {
                int row = rowb + r;
                if (row < M) {
                    float v = acc[i][j][r] + bcol;
                    if (RELU) v = fmaxf(v, 0.f);
                    store_c(Cout + (size_t)row * N + col, v);
                }
            }
        }
    }
}

// ---------------------------------------------------------------- softmax16
__global__ __launch_bounds__(256)
void softmax16_kernel(float* __restrict__ x, int ngroups) {
    int i = blockIdx.x * 256 + threadIdx.x;
    if (i >= ngroups) return;
    float* p = x + (size_t)i * 16;
    float v[16];
    float4* p4 = (float4*)p;
    #pragma unroll
    for (int j = 0; j < 4; j++) {
        float4 t = p4[j];
        v[4*j+0] = t.x; v[4*j+1] = t.y; v[4*j+2] = t.z; v[4*j+3] = t.w;
    }
    float mx = v[0];
    #pragma unroll
    for (int j = 1; j < 16; j++) mx = fmaxf(mx, v[j]);
    float sm = 0.f;
    #pragma unroll
    for (int j = 0; j < 16; j++) { v[j] = __expf(v[j] - mx); sm += v[j]; }
    float inv = 1.f / sm;
    #pragma unroll
    for (int j = 0; j < 4; j++)
        p4[j] = make_float4(v[4*j]*inv, v[4*j+1]*inv, v[4*j+2]*inv, v[4*j+3]*inv);
}

// ---------------------------------------------------------------- sampling v2
__global__ __launch_bounds__(256)
void sample_kernel(const bf16_t* __restrict__ value, const float* __restrict__ off,
                   const float* __restrict__ attn, bf16_t* __restrict__ out) {
    int gw   = blockIdx.x * 4 + (threadIdx.x >> 6);
    int lane = threadIdx.x & 63;
    if (gw >= 2 * S_LEN * 8) return;
    int h  = gw & 7;
    int bs = gw >> 3;
    int b  = bs / S_LEN;
    int s  = bs - b * S_LEN;

    float rx, ry;
    if (s < 6400)      { int i = s;        float inv = 1.f/80.f; ry = ((i/80) + 0.5f)*inv; rx = ((i%80) + 0.5f)*inv; }
    else if (s < 8000) { int i = s - 6400; float inv = 1.f/40.f; ry = ((i/40) + 0.5f)*inv; rx = ((i%40) + 0.5f)*inv; }
    else if (s < 8400) { int i = s - 8000; float inv = 1.f/20.f; ry = ((i/20) + 0.5f)*inv; rx = ((i%20) + 0.5f)*inv; }
    else               { int i = s - 8400; float inv = 1.f/10.f; ry = ((i/10) + 0.5f)*inv; rx = ((i%10) + 0.5f)*inv; }

    const int WH[4]  = {80, 40, 20, 10};
    const int LST[4] = {0, 6400, 8000, 8400};

    // phase 1: lane = (point, corner)
    int pt = lane >> 2;
    int cn = lane & 3;
    int ll = pt >> 2;
    int W  = WH[ll];
    float2 o2 = *(const float2*)(off + ((size_t)bs * 8 + h) * 32 + pt * 2);
    float  aw = attn[((size_t)bs * 8 + h) * 16 + pt];
    float x = fmaf(rx, (float)W, o2.x) - 0.5f;
    float y = fmaf(ry, (float)W, o2.y) - 0.5f;
    float fx = floorf(x), fy = floorf(y);
    float wx = x - fx,  wy = y - fy;
    int cx = (int)fx + (cn & 1);
    int cy = (int)fy + (cn >> 1);
    float wgt = aw * ((cn & 1) ? wx : 1.f - wx) * ((cn >> 1) ? wy : 1.f - wy);
    bool valid = (cx >= 0) && (cx < W) && (cy >= 0) && (cy < W);
    if (!valid) wgt = 0.f;
    int xc = min(max(cx, 0), W - 1);
    int yc = min(max(cy, 0), W - 1);
    int addr = LST[ll] + yc * W + xc;

    // phase 2: vectorized gather
    const bf16_t* vb = value + ((size_t)b * S_LEN) * 512 + h * 64 + (lane & 7) * 8;
    int sub = lane >> 3;
    float acc[8];
    #pragma unroll
    for (int j = 0; j < 8; j++) acc[j] = 0.f;
    #pragma unroll
    for (int it = 0; it < 8; it++) {
        int pair = it * 8 + sub;
        int   a = __shfl(addr, pair, 64);
        float w = __shfl(wgt,  pair, 64);
        bf16x8 v = *(const bf16x8*)(vb + (size_t)a * 512);
        #pragma unroll
        for (int j = 0; j < 8; j++) acc[j] += w * (float)v[j];
    }

    // phase 3: reduce over pair-groups
    #pragma unroll
    for (int o = 8; o < 64; o <<= 1)
        #pragma unroll
        for (int j = 0; j < 8; j++) acc[j] += __shfl_xor(acc[j], o, 64);

    if (lane < 8) {
        bf16x8 ov;
        #pragma unroll
        for (int j = 0; j < 8; j++) ov[j] = (bf16_t)acc[j];
        *(bf16x8*)(out + (size_t)bs * 512 + h * 64 + lane * 8) = ov;
    }
}

// ---------------------------------------------------------------- LayerNorm
template<typename INA, typename INB, typename OT>
__global__ __launch_bounds__(256)
void ln_kernel(const INA* __restrict__ Xa, const INB* __restrict__ Xb,
               const float* __restrict__ g, const float* __restrict__ be,
               OT* __restrict__ out, int M) {
    int wave = threadIdx.x >> 6;
    int lane = threadIdx.x & 63;
    int row = blockIdx.x * 4 + wave;
    if (row >= M) return;
    size_t base = (size_t)row * 512;
    float v[8];
    float s = 0.f, sq = 0.f;
    #pragma unroll
    for (int p = 0; p < 2; p++) {
        int idx = p * 256 + lane * 4;
        float4 a4 = load4f(Xa + base + idx);
        float4 b4 = load4f(Xb + base + idx);
        float t0 = a4.x + b4.x, t1 = a4.y + b4.y, t2 = a4.z + b4.z, t3 = a4.w + b4.w;
        v[p*4+0] = t0; v[p*4+1] = t1; v[p*4+2] = t2; v[p*4+3] = t3;
        s  += t0 + t1 + t2 + t3;
        sq += t0*t0 + t1*t1 + t2*t2 + t3*t3;
    }
    #pragma unroll
    for (int off = 32; off > 0; off >>= 1) {
        s  += __shfl_xor(s, off, 64);
        sq += __shfl_xor(sq, off, 64);
    }
    float mean = s * (1.f / 512.f);
    float var  = sq * (1.f / 512.f) - mean * mean;
    float rstd = rsqrtf(var + 1e-5f);
    #pragma unroll
    for (int p = 0; p < 2; p++) {
        int idx = p * 256 + lane * 4;
        #pragma unroll
        for (int j = 0; j < 4; j++) {
            int col = idx + j;
            float o = (v[p*4+j] - mean) * rstd * g[col] + be[col];
            store_c(out + base + col, o);
        }
    }
}

// ---------------------------------------------------------------- launch
extern "C" void kernel_launch(void* const* d_in, const int* in_sizes, int n_in,
                              void* d_out, int out_size, void* d_ws, size_t ws_size,
                              hipStream_t stream) {
    const float* src    = (const float*)d_in[0];
    const float* pos    = (const float*)d_in[1];
    const float* w_off  = (const float*)d_in[2];
    const float* b_off  = (const float*)d_in[3];
    const float* w_attn = (const float*)d_in[4];
    const float* b_attn = (const float*)d_in[5];
    const float* w_val  = (const float*)d_in[6];
    const float* b_val  = (const float*)d_in[7];
    const float* w_out  = (const float*)d_in[8];
    const float* b_out  = (const float*)d_in[9];
    const float* ln1_g  = (const float*)d_in[10];
    const float* ln1_b  = (const float*)d_in[11];
    const float* w1     = (const float*)d_in[12];
    const float* b1     = (const float*)d_in[13];
    const float* w2     = (const float*)d_in[14];
    const float* b2     = (const float*)d_in[15];
    const float* ln2_g  = (const float*)d_in[16];
    const float* ln2_b  = (const float*)d_in[17];

    const int M = M_ROWS;
    char* ws = (char*)d_ws;
    size_t o = 0;
    auto alloc = [&](size_t bytes) { size_t r = o; o += (bytes + 255) & ~(size_t)255; return r; };

    size_t off_q       = alloc((size_t)M * 512 * 2);   // bf16
    size_t off_srcbf   = alloc((size_t)M * 512 * 2);   // bf16
    size_t off_value   = alloc((size_t)M * 512 * 2);   // bf16
    size_t off_sampled = alloc((size_t)M * 512 * 2);   // bf16
    size_t off_offtmp  = alloc((size_t)M * 256 * 4);   // f32
    size_t off_attntmp = alloc((size_t)M * 128 * 4);   // f32
    size_t off_attnout = alloc((size_t)M * 512 * 2);   // bf16
    size_t off_x       = alloc((size_t)M * 512 * 2);   // bf16
    // transposed bf16 weights
    size_t off_wtval   = alloc((size_t)512 * 512 * 2);
    size_t off_wtoff   = alloc((size_t)256 * 512 * 2);
    size_t off_wtattn  = alloc((size_t)128 * 512 * 2);
    size_t off_wtout   = alloc((size_t)512 * 512 * 2);
    size_t off_wtw1    = alloc((size_t)1024 * 512 * 2);
    size_t off_wtw2    = alloc((size_t)512 * 1024 * 2);

    bf16_t* q        = (bf16_t*)(ws + off_q);
    bf16_t* src_bf   = (bf16_t*)(ws + off_srcbf);
    bf16_t* value    = (bf16_t*)(ws + off_value);
    bf16_t* sampled  = (bf16_t*)(ws + off_sampled);
    float*  offtmp   = (float*)(ws + off_offtmp);
    float*  attntmp  = (float*)(ws + off_attntmp);
    bf16_t* attn_out = (bf16_t*)(ws + off_attnout);
    bf16_t* x        = (bf16_t*)(ws + off_x);
    bf16_t* hidden   = (bf16_t*)(ws + off_sampled);   // alias: sampled+offtmp dead (34.8MB contiguous)
    bf16_t* ffn_out  = (bf16_t*)(ws + off_attntmp);   // alias: attntmp+attn_out dead
    bf16_t* wt_val   = (bf16_t*)(ws + off_wtval);
    bf16_t* wt_off   = (bf16_t*)(ws + off_wtoff);
    bf16_t* wt_attn  = (bf16_t*)(ws + off_wtattn);
    bf16_t* wt_out   = (bf16_t*)(ws + off_wtout);
    bf16_t* wt_w1    = (bf16_t*)(ws + off_wtw1);
    bf16_t* wt_w2    = (bf16_t*)(ws + off_wtw2);
    float*  outp     = (float*)d_out;

    // ---- weight transposes (f32 [K][N] -> bf16 [N][K])
    transpose_kernel<<<dim3(512/32,  512/32), 256, 0, stream>>>(w_val,  wt_val,  512,  512);
    transpose_kernel<<<dim3(512/32,  256/32), 256, 0, stream>>>(w_off,  wt_off,  512,  256);
    transpose_kernel<<<dim3(512/32,  128/32), 256, 0, stream>>>(w_attn, wt_attn, 512,  128);
    transpose_kernel<<<dim3(512/32,  512/32), 256, 0, stream>>>(w_out,  wt_out,  512,  512);
    transpose_kernel<<<dim3(512/32, 1024/32), 256, 0, stream>>>(w1,     wt_w1,   512, 1024);
    transpose_kernel<<<dim3(1024/32, 512/32), 256, 0, stream>>>(w2,     wt_w2,  1024,  512);

    add_q_kernel<<<(M * 512 / 4 + 255) / 256, 256, 0, stream>>>(src, pos, q, src_bf, M * 512 / 4);

    const int MT = (M + 127) / 128;   // 133

    gemm128_kernel<bf16_t, false><<<dim3(MT, 4), 256, 0, stream>>>(src_bf, wt_val, b_val, value, M, 512, 512);
    gemm128_kernel<float,  false><<<dim3(MT, 2), 256, 0, stream>>>(q, wt_off,  b_off,  offtmp,  M, 256, 512);
    gemm128_kernel<float,  false><<<dim3(MT, 1), 256, 0, stream>>>(q, wt_attn, b_attn, attntmp, M, 128, 512);

    softmax16_kernel<<<(M * 8 + 255) / 256, 256, 0, stream>>>(attntmp, M * 8);

    sample_kernel<<<(M * 8) / 4, 256, 0, stream>>>(value, offtmp, attntmp, sampled);

    gemm128_kernel<bf16_t, false><<<dim3(MT, 4), 256, 0, stream>>>(sampled, wt_out, b_out, attn_out, M, 512, 512);

    ln_kernel<float, bf16_t, bf16_t><<<(M + 3) / 4, 256, 0, stream>>>(src, attn_out, ln1_g, ln1_b, x, M);

    gemm128_kernel<bf16_t, true ><<<dim3(MT, 8), 256, 0, stream>>>(x, wt_w1, b1, hidden, M, 1024, 512);
    gemm128_kernel<bf16_t, false><<<dim3(MT, 4), 256, 0, stream>>>(hidden, wt_w2, b2, ffn_out, M, 512, 1024);

    ln_kernel<bf16_t, bf16_t, float><<<(M + 3) / 4, 256, 0, stream>>>(x, ffn_out, ln2_g, ln2_b, outp, M);
}

// Round 6
// 439.836 us; speedup vs baseline: 2.5858x; 1.0238x over previous
//
#include <hip/hip_runtime.h>

// ---------------------------------------------------------------------------
// DeformableTransformer encoder layer, MI355X (gfx950).
// R5->R6: GEMM staging via global_load_lds width=16 (async DMA, unpadded
// [128][32] LDS); off+attn GEMMs fused into one N=384 GEMM; softmax fused
// into sample_kernel (wave-level reduce); sample inner loop packed-f32.
// ---------------------------------------------------------------------------

typedef __bf16 bf16_t;
typedef __bf16 bf16x8 __attribute__((ext_vector_type(8)));
typedef __bf16 bf16x4 __attribute__((ext_vector_type(4)));
typedef float  f32x4  __attribute__((ext_vector_type(4)));
typedef float  f32x2  __attribute__((ext_vector_type(2)));
typedef unsigned int u32x4 __attribute__((ext_vector_type(4)));

#define M_ROWS 17000   // B*S
#define S_LEN  8500

// ---------------------------------------------------------------- helpers
__device__ inline void store_c(float* p, float v)  { *p = v; }
__device__ inline void store_c(bf16_t* p, float v) { *p = (bf16_t)v; }

__device__ inline float4 load4f(const float* p)  { return *(const float4*)p; }
__device__ inline float4 load4f(const bf16_t* p) {
    bf16x4 v = *(const bf16x4*)p;
    return make_float4((float)v[0], (float)v[1], (float)v[2], (float)v[3]);
}

// async global->LDS, 16B per lane; LDS dest = wave-uniform base + lane*16
__device__ __forceinline__ void gload_lds16(const bf16_t* g, bf16_t* l) {
    __builtin_amdgcn_global_load_lds(
        (const __attribute__((address_space(1))) void*)g,
        (__attribute__((address_space(3))) void*)l,
        16, 0, 0);
}

// ---------------------------------------------------------------- weight T
// in: f32 [K][N] -> out: bf16 [N][K]; 32x32 LDS tiles, block 256 (32x8)
__global__ __launch_bounds__(256)
void transpose_kernel(const float* __restrict__ in, bf16_t* __restrict__ out,
                      int K, int N) {
    __shared__ float s[32][33];
    int tx = threadIdx.x & 31, ty = threadIdx.x >> 5;   // ty 0..7
    int k0 = blockIdx.x * 32, n0 = blockIdx.y * 32;
    #pragma unroll
    for (int i = 0; i < 4; i++)
        s[ty + 8 * i][tx] = in[(size_t)(k0 + ty + 8 * i) * N + n0 + tx];
    __syncthreads();
    #pragma unroll
    for (int i = 0; i < 4; i++)
        out[(size_t)(n0 + ty + 8 * i) * K + k0 + tx] = (bf16_t)s[tx][ty + 8 * i];
}

// ---------------------------------------------------------------- bias concat
__global__ __launch_bounds__(384)
void prep_bias_kernel(const float* __restrict__ b_off, const float* __restrict__ b_attn,
                      float* __restrict__ bias_oa) {
    int i = threadIdx.x;
    bias_oa[i] = (i < 256) ? b_off[i] : b_attn[i - 256];
}

// ---------------------------------------------------------------- q = src+pos
__global__ __launch_bounds__(256)
void add_q_kernel(const float* __restrict__ a, const float* __restrict__ b,
                  bf16_t* __restrict__ q, bf16_t* __restrict__ src_bf, int n4) {
    int i = blockIdx.x * 256 + threadIdx.x;
    if (i >= n4) return;
    float4 av = *(const float4*)(a + (size_t)i * 4);
    float4 bv = *(const float4*)(b + (size_t)i * 4);
    bf16x4 sv, ov;
    sv[0] = (bf16_t)av.x; sv[1] = (bf16_t)av.y; sv[2] = (bf16_t)av.z; sv[3] = (bf16_t)av.w;
    ov[0] = (bf16_t)(av.x + bv.x);
    ov[1] = (bf16_t)(av.y + bv.y);
    ov[2] = (bf16_t)(av.z + bv.z);
    ov[3] = (bf16_t)(av.w + bv.w);
    *(bf16x4*)(q      + (size_t)i * 4) = ov;
    *(bf16x4*)(src_bf + (size_t)i * 4) = sv;
}

// ---------------------------------------------------------------- GEMM 128x128
// C[M,N] = A[M,K] @ Wt[N,K]^T + bias, optional ReLU. A,Wt bf16.
// BK=32, unpadded LDS [128][32], staging via global_load_lds (16B/lane):
// wave w stages rows [32w,32w+32) of A and B as 2 contiguous 1KB chunks each.
// Wave (wr,wc) computes 64x64 via 4x4 MFMA 16x16x32.
template<typename OT, bool RELU>
__global__ __launch_bounds__(256)
void gemm128_kernel(const bf16_t* __restrict__ A, const bf16_t* __restrict__ Wt,
                    const float* __restrict__ bias, OT* __restrict__ Cout,
                    int M, int N, int K) {
    __shared__ bf16_t As[128][32];
    __shared__ bf16_t Bs[128][32];

    const int tid  = threadIdx.x;
    const int wave = tid >> 6;
    const int lane = tid & 63;
    const int quad = lane >> 4;
    const int lq   = lane & 15;
    const int wr   = (wave >> 1) * 64;
    const int wc   = (wave & 1) * 64;
    const int row0 = blockIdx.x * 128;
    const int col0 = blockIdx.y * 128;

    // staging addresses: lane l covers row (l>>2), kcols (l&3)*8..+8 of chunk
    const int srow  = lane >> 2;
    const int skcol = (lane & 3) * 8;
    int ra = row0 + wave * 32 + srow;
    const bf16_t* gA0 = A + (size_t)min(ra,      M - 1) * K + skcol;
    const bf16_t* gA1 = A + (size_t)min(ra + 16, M - 1) * K + skcol;
    const bf16_t* gB0 = Wt + (size_t)(col0 + wave * 32 + srow) * K + skcol;
    const bf16_t* gB1 = gB0 + (size_t)16 * K;
    bf16_t* lA0 = &As[wave * 32][0];
    bf16_t* lA1 = &As[wave * 32 + 16][0];
    bf16_t* lB0 = &Bs[wave * 32][0];
    bf16_t* lB1 = &Bs[wave * 32 + 16][0];

    f32x4 acc[4][4];
    #pragma unroll
    for (int i = 0; i < 4; i++)
        #pragma unroll
        for (int j = 0; j < 4; j++)
            #pragma unroll
            for (int r = 0; r < 4; r++) acc[i][j][r] = 0.f;

    for (int kk = 0; kk < K; kk += 32) {
        gload_lds16(gA0 + kk, lA0);
        gload_lds16(gA1 + kk, lA1);
        gload_lds16(gB0 + kk, lB0);
        gload_lds16(gB1 + kk, lB1);
        __syncthreads();

        bf16x8 af[4], bfr[4];
        #pragma unroll
        for (int i = 0; i < 4; i++)
            af[i] = *(const bf16x8*)&As[wr + i * 16 + lq][quad * 8];
        #pragma unroll
        for (int j = 0; j < 4; j++)
            bfr[j] = *(const bf16x8*)&Bs[wc + j * 16 + lq][quad * 8];
        #pragma unroll
        for (int i = 0; i < 4; i++)
            #pragma unroll
            for (int j = 0; j < 4; j++)
                acc[i][j] = __builtin_amdgcn_mfma_f32_16x16x32_bf16(af[i], bfr[j], acc[i][j], 0, 0, 0);
        __syncthreads();
    }

    // ---- epilogue: D col = lq, row = quad*4+r
    #pragma unroll
    for (int j = 0; j < 4; j++) {
        int col = col0 + wc + j * 16 + lq;
        float bcol = bias[col];
        #pragma unroll
        for (int i = 0; i < 4; i++) {
            int rowb = row0 + wr + i * 16 + quad * 4;
            #pragma unroll
            for (int r = 0; r < 4; r++) {
                int row = rowb + r;
                if (row < M) {
                    float v = acc[i][j][r] + bcol;
                    if (RELU) v = fmaxf(v, 0.f);
                    store_c(Cout + (size_t)row * N + col, v);
                }
            }
        }
    }
}

// ---------------------------------------------------------------- sampling v3
// one wave per (b, s, head); softmax over the 16 attn logits done in-wave.
// oa layout per token row (stride 384): [0..255] offsets (h*32+pt*2),
// [256..383] attn logits (h*16+pt).
__global__ __launch_bounds__(256)
void sample_kernel(const bf16_t* __restrict__ value, const float* __restrict__ oa,
                   bf16_t* __restrict__ out) {
    int gw   = blockIdx.x * 4 + (threadIdx.x >> 6);
    int lane = threadIdx.x & 63;
    if (gw >= 2 * S_LEN * 8) return;
    int h  = gw & 7;
    int bs = gw >> 3;
    int b  = bs / S_LEN;
    int s  = bs - b * S_LEN;

    float rx, ry;
    if (s < 6400)      { int i = s;        float inv = 1.f/80.f; ry = ((i/80) + 0.5f)*inv; rx = ((i%80) + 0.5f)*inv; }
    else if (s < 8000) { int i = s - 6400; float inv = 1.f/40.f; ry = ((i/40) + 0.5f)*inv; rx = ((i%40) + 0.5f)*inv; }
    else if (s < 8400) { int i = s - 8000; float inv = 1.f/20.f; ry = ((i/20) + 0.5f)*inv; rx = ((i%20) + 0.5f)*inv; }
    else               { int i = s - 8400; float inv = 1.f/10.f; ry = ((i/10) + 0.5f)*inv; rx = ((i%10) + 0.5f)*inv; }

    const int WH[4]  = {80, 40, 20, 10};
    const int LST[4] = {0, 6400, 8000, 8400};

    // phase 1: lane = (point, corner); each pt appears on 4 lanes
    int pt = lane >> 2;
    int cn = lane & 3;
    int ll = pt >> 2;
    int W  = WH[ll];
    const float* row = oa + (size_t)bs * 384;
    float2 o2 = *(const float2*)(row + h * 32 + pt * 2);
    float logit = row[256 + h * 16 + pt];

    // in-wave softmax over 16 pts (each counted 4x; max unaffected, sum = 4*true)
    float mxv = logit;
    #pragma unroll
    for (int o = 1; o < 64; o <<= 1) mxv = fmaxf(mxv, __shfl_xor(mxv, o, 64));
    float e = __expf(logit - mxv);
    float se = e;
    #pragma unroll
    for (int o = 1; o < 64; o <<= 1) se += __shfl_xor(se, o, 64);
    float aw = e * 4.f * __builtin_amdgcn_rcpf(se);

    float x = fmaf(rx, (float)W, o2.x) - 0.5f;
    float y = fmaf(ry, (float)W, o2.y) - 0.5f;
    float fx = floorf(x), fy = floorf(y);
    float wx = x - fx,  wy = y - fy;
    int cx = (int)fx + (cn & 1);
    int cy = (int)fy + (cn >> 1);
    float wgt = aw * ((cn & 1) ? wx : 1.f - wx) * ((cn >> 1) ? wy : 1.f - wy);
    bool valid = (cx >= 0) && (cx < W) && (cy >= 0) && (cy < W);
    if (!valid) wgt = 0.f;
    int xc = min(max(cx, 0), W - 1);
    int yc = min(max(cy, 0), W - 1);
    int addr = LST[ll] + yc * W + xc;

    // phase 2: vectorized gather, packed-f32 accumulate
    const bf16_t* vb = value + ((size_t)b * S_LEN) * 512 + h * 64 + (lane & 7) * 8;
    int sub = lane >> 3;
    f32x2 acc2[4];
    #pragma unroll
    for (int j = 0; j < 4; j++) { acc2[j][0] = 0.f; acc2[j][1] = 0.f; }
    #pragma unroll
    for (int it = 0; it < 8; it++) {
        int pair = it * 8 + sub;
        int   a = __shfl(addr, pair, 64);
        float w = __shfl(wgt,  pair, 64);
        u32x4 d = *(const u32x4*)(vb + (size_t)a * 512);
        f32x2 w2; w2[0] = w; w2[1] = w;
        #pragma unroll
        for (int j = 0; j < 4; j++) {
            f32x2 v2;
            v2[0] = __uint_as_float(d[j] << 16);
            v2[1] = __uint_as_float(d[j] & 0xffff0000u);
            acc2[j] += w2 * v2;
        }
    }

    // phase 3: reduce over the 8 pair-groups (lane bits 3..5)
    #pragma unroll
    for (int o = 8; o < 64; o <<= 1)
        #pragma unroll
        for (int j = 0; j < 4; j++) {
            acc2[j][0] += __shfl_xor(acc2[j][0], o, 64);
            acc2[j][1] += __shfl_xor(acc2[j][1], o, 64);
        }

    if (lane < 8) {
        bf16x8 ov;
        #pragma unroll
        for (int j = 0; j < 4; j++) {
            ov[2*j]   = (bf16_t)acc2[j][0];
            ov[2*j+1] = (bf16_t)acc2[j][1];
        }
        *(bf16x8*)(out + (size_t)bs * 512 + h * 64 + lane * 8) = ov;
    }
}

// ---------------------------------------------------------------- LayerNorm
template<typename INA, typename INB, typename OT>
__global__ __launch_bounds__(256)
void ln_kernel(const INA* __restrict__ Xa, const INB* __restrict__ Xb,
               const float* __restrict__ g, const float* __restrict__ be,
               OT* __restrict__ out, int M) {
    int wave = threadIdx.x >> 6;
    int lane = threadIdx.x & 63;
    int row = blockIdx.x * 4 + wave;
    if (row >= M) return;
    size_t base = (size_t)row * 512;
    float v[8];
    float s = 0.f, sq = 0.f;
    #pragma unroll
    for (int p = 0; p < 2; p++) {
        int idx = p * 256 + lane * 4;
        float4 a4 = load4f(Xa + base + idx);
        float4 b4 = load4f(Xb + base + idx);
        float t0 = a4.x + b4.x, t1 = a4.y + b4.y, t2 = a4.z + b4.z, t3 = a4.w + b4.w;
        v[p*4+0] = t0; v[p*4+1] = t1; v[p*4+2] = t2; v[p*4+3] = t3;
        s  += t0 + t1 + t2 + t3;
        sq += t0*t0 + t1*t1 + t2*t2 + t3*t3;
    }
    #pragma unroll
    for (int off = 32; off > 0; off >>= 1) {
        s  += __shfl_xor(s, off, 64);
        sq += __shfl_xor(sq, off, 64);
    }
    float mean = s * (1.f / 512.f);
    float var  = sq * (1.f / 512.f) - mean * mean;
    float rstd = rsqrtf(var + 1e-5f);
    #pragma unroll
    for (int p = 0; p < 2; p++) {
        int idx = p * 256 + lane * 4;
        #pragma unroll
        for (int j = 0; j < 4; j++) {
            int col = idx + j;
            float o = (v[p*4+j] - mean) * rstd * g[col] + be[col];
            store_c(out + base + col, o);
        }
    }
}

// ---------------------------------------------------------------- launch
extern "C" void kernel_launch(void* const* d_in, const int* in_sizes, int n_in,
                              void* d_out, int out_size, void* d_ws, size_t ws_size,
                              hipStream_t stream) {
    const float* src    = (const float*)d_in[0];
    const float* pos    = (const float*)d_in[1];
    const float* w_off  = (const float*)d_in[2];
    const float* b_off  = (const float*)d_in[3];
    const float* w_attn = (const float*)d_in[4];
    const float* b_attn = (const float*)d_in[5];
    const float* w_val  = (const float*)d_in[6];
    const float* b_val  = (const float*)d_in[7];
    const float* w_out  = (const float*)d_in[8];
    const float* b_out  = (const float*)d_in[9];
    const float* ln1_g  = (const float*)d_in[10];
    const float* ln1_b  = (const float*)d_in[11];
    const float* w1     = (const float*)d_in[12];
    const float* b1     = (const float*)d_in[13];
    const float* w2     = (const float*)d_in[14];
    const float* b2     = (const float*)d_in[15];
    const float* ln2_g  = (const float*)d_in[16];
    const float* ln2_b  = (const float*)d_in[17];

    const int M = M_ROWS;
    char* ws = (char*)d_ws;
    size_t o = 0;
    auto alloc = [&](size_t bytes) { size_t r = o; o += (bytes + 255) & ~(size_t)255; return r; };

    size_t off_q       = alloc((size_t)M * 512 * 2);   // bf16
    size_t off_srcbf   = alloc((size_t)M * 512 * 2);   // bf16
    size_t off_value   = alloc((size_t)M * 512 * 2);   // bf16
    size_t off_sampled = alloc((size_t)M * 512 * 2);   // bf16
    size_t off_oa      = alloc((size_t)M * 384 * 4);   // f32 (offsets + attn logits)
    size_t off_attnout = alloc((size_t)M * 512 * 2);   // bf16
    size_t off_x       = alloc((size_t)M * 512 * 2);   // bf16
    // transposed bf16 weights
    size_t off_wtval   = alloc((size_t)512 * 512 * 2);
    size_t off_wtoa    = alloc((size_t)384 * 512 * 2);
    size_t off_wtout   = alloc((size_t)512 * 512 * 2);
    size_t off_wtw1    = alloc((size_t)1024 * 512 * 2);
    size_t off_wtw2    = alloc((size_t)512 * 1024 * 2);
    size_t off_boa     = alloc((size_t)384 * 4);

    bf16_t* q        = (bf16_t*)(ws + off_q);
    bf16_t* src_bf   = (bf16_t*)(ws + off_srcbf);
    bf16_t* value    = (bf16_t*)(ws + off_value);
    bf16_t* sampled  = (bf16_t*)(ws + off_sampled);
    float*  oa       = (float*)(ws + off_oa);
    bf16_t* attn_out = (bf16_t*)(ws + off_attnout);
    bf16_t* x        = (bf16_t*)(ws + off_x);
    bf16_t* hidden   = (bf16_t*)(ws + off_sampled);   // alias: sampled(17.4M)+oa(26.1M) dead, need 34.8M
    bf16_t* ffn_out  = (bf16_t*)(ws + off_attnout);   // alias: attn_out dead after ln1
    bf16_t* wt_val   = (bf16_t*)(ws + off_wtval);
    bf16_t* wt_oa    = (bf16_t*)(ws + off_wtoa);
    bf16_t* wt_out   = (bf16_t*)(ws + off_wtout);
    bf16_t* wt_w1    = (bf16_t*)(ws + off_wtw1);
    bf16_t* wt_w2    = (bf16_t*)(ws + off_wtw2);
    float*  bias_oa  = (float*)(ws + off_boa);
    float*  outp     = (float*)d_out;

    // ---- weight transposes (f32 [K][N] -> bf16 [N][K]); off+attn concat into wt_oa
    transpose_kernel<<<dim3(512/32,  512/32), 256, 0, stream>>>(w_val,  wt_val,  512,  512);
    transpose_kernel<<<dim3(512/32,  256/32), 256, 0, stream>>>(w_off,  wt_oa,   512,  256);
    transpose_kernel<<<dim3(512/32,  128/32), 256, 0, stream>>>(w_attn, wt_oa + (size_t)256*512, 512, 128);
    transpose_kernel<<<dim3(512/32,  512/32), 256, 0, stream>>>(w_out,  wt_out,  512,  512);
    transpose_kernel<<<dim3(512/32, 1024/32), 256, 0, stream>>>(w1,     wt_w1,   512, 1024);
    transpose_kernel<<<dim3(1024/32, 512/32), 256, 0, stream>>>(w2,     wt_w2,  1024,  512);
    prep_bias_kernel<<<1, 384, 0, stream>>>(b_off, b_attn, bias_oa);

    add_q_kernel<<<(M * 512 / 4 + 255) / 256, 256, 0, stream>>>(src, pos, q, src_bf, M * 512 / 4);

    const int MT = (M + 127) / 128;   // 133

    gemm128_kernel<bf16_t, false><<<dim3(MT, 4), 256, 0, stream>>>(src_bf, wt_val, b_val, value, M, 512, 512);
    gemm128_kernel<float,  false><<<dim3(MT, 3), 256, 0, stream>>>(q, wt_oa, bias_oa, oa, M, 384, 512);

    sample_kernel<<<(M * 8) / 4, 256, 0, stream>>>(value, oa, sampled);

    gemm128_kernel<bf16_t, false><<<dim3(MT, 4), 256, 0, stream>>>(sampled, wt_out, b_out, attn_out, M, 512, 512);

    ln_kernel<float, bf16_t, bf16_t><<<(M + 3) / 4, 256, 0, stream>>>(src, attn_out, ln1_g, ln1_b, x, M);

    gemm128_kernel<bf16_t, true ><<<dim3(MT, 8), 256, 0, stream>>>(x, wt_w1, b1, hidden, M, 1024, 512);
    gemm128_kernel<bf16_t, false><<<dim3(MT, 4), 256, 0, stream>>>(hidden, wt_w2, b2, ffn_out, M, 512, 1024);

    ln_kernel<bf16_t, bf16_t, float><<<(M + 3) / 4, 256, 0, stream>>>(x, ffn_out, ln2_g, ln2_b, outp, M);
}

// Round 7
// 422.480 us; speedup vs baseline: 2.6920x; 1.0411x over previous
//
#include <hip/hip_runtime.h>

// ---------------------------------------------------------------------------
// DeformableTransformer encoder layer, MI355X (gfx950).
// R7: GEMM = register-prefetch double-buffered LDS (one barrier/iter,
// global-load latency hidden under MFMA); padded stride-40 LDS (conflict-
// free staging+frag reads). Sample reverted to R5-proven form (scalar cvt,
// separate strided softmax); keeps fused N=384 off+attn GEMM.
// ---------------------------------------------------------------------------

typedef __bf16 bf16_t;
typedef __bf16 bf16x8 __attribute__((ext_vector_type(8)));
typedef __bf16 bf16x4 __attribute__((ext_vector_type(4)));
typedef float  f32x4  __attribute__((ext_vector_type(4)));

#define M_ROWS 17000   // B*S
#define S_LEN  8500

// ---------------------------------------------------------------- helpers
__device__ inline void store_c(float* p, float v)  { *p = v; }
__device__ inline void store_c(bf16_t* p, float v) { *p = (bf16_t)v; }

__device__ inline float4 load4f(const float* p)  { return *(const float4*)p; }
__device__ inline float4 load4f(const bf16_t* p) {
    bf16x4 v = *(const bf16x4*)p;
    return make_float4((float)v[0], (float)v[1], (float)v[2], (float)v[3]);
}

// ---------------------------------------------------------------- weight T
// in: f32 [K][N] -> out: bf16 [N][K]; 32x32 LDS tiles, block 256 (32x8)
__global__ __launch_bounds__(256)
void transpose_kernel(const float* __restrict__ in, bf16_t* __restrict__ out,
                      int K, int N) {
    __shared__ float s[32][33];
    int tx = threadIdx.x & 31, ty = threadIdx.x >> 5;   // ty 0..7
    int k0 = blockIdx.x * 32, n0 = blockIdx.y * 32;
    #pragma unroll
    for (int i = 0; i < 4; i++)
        s[ty + 8 * i][tx] = in[(size_t)(k0 + ty + 8 * i) * N + n0 + tx];
    __syncthreads();
    #pragma unroll
    for (int i = 0; i < 4; i++)
        out[(size_t)(n0 + ty + 8 * i) * K + k0 + tx] = (bf16_t)s[tx][ty + 8 * i];
}

// ---------------------------------------------------------------- bias concat
__global__ __launch_bounds__(384)
void prep_bias_kernel(const float* __restrict__ b_off, const float* __restrict__ b_attn,
                      float* __restrict__ bias_oa) {
    int i = threadIdx.x;
    bias_oa[i] = (i < 256) ? b_off[i] : b_attn[i - 256];
}

// ---------------------------------------------------------------- q = src+pos
__global__ __launch_bounds__(256)
void add_q_kernel(const float* __restrict__ a, const float* __restrict__ b,
                  bf16_t* __restrict__ q, bf16_t* __restrict__ src_bf, int n4) {
    int i = blockIdx.x * 256 + threadIdx.x;
    if (i >= n4) return;
    float4 av = *(const float4*)(a + (size_t)i * 4);
    float4 bv = *(const float4*)(b + (size_t)i * 4);
    bf16x4 sv, ov;
    sv[0] = (bf16_t)av.x; sv[1] = (bf16_t)av.y; sv[2] = (bf16_t)av.z; sv[3] = (bf16_t)av.w;
    ov[0] = (bf16_t)(av.x + bv.x);
    ov[1] = (bf16_t)(av.y + bv.y);
    ov[2] = (bf16_t)(av.z + bv.z);
    ov[3] = (bf16_t)(av.w + bv.w);
    *(bf16x4*)(q      + (size_t)i * 4) = ov;
    *(bf16x4*)(src_bf + (size_t)i * 4) = sv;
}

// ---------------------------------------------------------------- GEMM 128x128
// C[M,N] = A[M,K] @ Wt[N,K]^T + bias, optional ReLU. A,Wt bf16.
// BK=32, double-buffered padded LDS, register prefetch across the single
// per-iteration barrier: barrier -> [global loads fly || MFMA on cur buf]
// -> vmcnt-wait at ds_write to alt buf -> barrier.
template<typename OT, bool RELU>
__global__ __launch_bounds__(256)
void gemm128_kernel(const bf16_t* __restrict__ A, const bf16_t* __restrict__ Wt,
                    const float* __restrict__ bias, OT* __restrict__ Cout,
                    int M, int N, int K) {
    __shared__ bf16_t As[2][128][40];
    __shared__ bf16_t Bs[2][128][40];

    const int tid  = threadIdx.x;
    const int wave = tid >> 6;
    const int lane = tid & 63;
    const int quad = lane >> 4;
    const int lq   = lane & 15;
    const int wr   = (wave >> 1) * 64;
    const int wc   = (wave & 1) * 64;
    const int row0 = blockIdx.x * 128;
    const int col0 = blockIdx.y * 128;

    const int sr = tid >> 2;          // 0..63 staging row
    const int sc = (tid & 3) * 8;     // staging k-offset

    const bf16_t* gA0 = A  + (size_t)min(row0 + sr,      M - 1) * K + sc;
    const bf16_t* gA1 = A  + (size_t)min(row0 + sr + 64, M - 1) * K + sc;
    const bf16_t* gB0 = Wt + (size_t)(col0 + sr) * K + sc;
    const bf16_t* gB1 = Wt + (size_t)(col0 + sr + 64) * K + sc;

    f32x4 acc[4][4];
    #pragma unroll
    for (int i = 0; i < 4; i++)
        #pragma unroll
        for (int j = 0; j < 4; j++)
            #pragma unroll
            for (int r = 0; r < 4; r++) acc[i][j][r] = 0.f;

    // prologue: chunk 0 into registers
    bf16x8 pa0 = *(const bf16x8*)gA0;
    bf16x8 pa1 = *(const bf16x8*)gA1;
    bf16x8 pb0 = *(const bf16x8*)gB0;
    bf16x8 pb1 = *(const bf16x8*)gB1;

    const int nIter = K >> 5;
    for (int it = 0; it < nIter; it++) {
        const int cur = it & 1;
        // stage current chunk (vmcnt wait on prefetch regs happens here)
        *(bf16x8*)&As[cur][sr][sc]      = pa0;
        *(bf16x8*)&As[cur][sr + 64][sc] = pa1;
        *(bf16x8*)&Bs[cur][sr][sc]      = pb0;
        *(bf16x8*)&Bs[cur][sr + 64][sc] = pb1;
        __syncthreads();

        // issue next chunk's global loads (in flight during MFMA below)
        if (it + 1 < nIter) {
            int ko = (it + 1) << 5;
            pa0 = *(const bf16x8*)(gA0 + ko);
            pa1 = *(const bf16x8*)(gA1 + ko);
            pb0 = *(const bf16x8*)(gB0 + ko);
            pb1 = *(const bf16x8*)(gB1 + ko);
        }

        bf16x8 af[4], bfr[4];
        #pragma unroll
        for (int i = 0; i < 4; i++)
            af[i] = *(const bf16x8*)&As[cur][wr + i * 16 + lq][quad * 8];
        #pragma unroll
        for (int j = 0; j < 4; j++)
            bfr[j] = *(const bf16x8*)&Bs[cur][wc + j * 16 + lq][quad * 8];
        #pragma unroll
        for (int i = 0; i < 4; i++)
            #pragma unroll
            for (int j = 0; j < 4; j++)
                acc[i][j] = __builtin_amdgcn_mfma_f32_16x16x32_bf16(af[i], bfr[j], acc[i][j], 0, 0, 0);
        // no second barrier: next iter writes the OTHER buffer; the next
        // barrier (lgkmcnt(0)) orders this iter's reads before any wave's
        // iter+2 overwrite of this buffer.
    }

    // ---- epilogue: D col = lq, row = quad*4+r
    #pragma unroll
    for (int j = 0; j < 4; j++) {
        int col = col0 + wc + j * 16 + lq;
        float bcol = bias[col];
        #pragma unroll
        for (int i = 0; i < 4; i++) {
            int rowb = row0 + wr + i * 16 + quad * 4;
            #pragma unroll
            for (int r = 0; r < 4; r++) {
                int row = rowb + r;
                if (row < M) {
                    float v = acc[i][j][r] + bcol;
                    if (RELU) v = fmaxf(v, 0.f);
                    store_c(Cout + (size_t)row * N + col, v);
                }
            }
        }
    }
}

// ---------------------------------------------------------------- softmax16
// in-place softmax over 16 logits per (token,head) inside oa rows:
// group i -> oa[(i>>3)*384 + 256 + (i&7)*16 .. +16]
__global__ __launch_bounds__(256)
void softmax16_kernel(float* __restrict__ oa, int ngroups) {
    int i = blockIdx.x * 256 + threadIdx.x;
    if (i >= ngroups) return;
    float* p = oa + (size_t)(i >> 3) * 384 + 256 + (i & 7) * 16;
    float v[16];
    float4* p4 = (float4*)p;
    #pragma unroll
    for (int j = 0; j < 4; j++) {
        float4 t = p4[j];
        v[4*j+0] = t.x; v[4*j+1] = t.y; v[4*j+2] = t.z; v[4*j+3] = t.w;
    }
    float mx = v[0];
    #pragma unroll
    for (int j = 1; j < 16; j++) mx = fmaxf(mx, v[j]);
    float sm = 0.f;
    #pragma unroll
    for (int j = 0; j < 16; j++) { v[j] = __expf(v[j] - mx); sm += v[j]; }
    float inv = 1.f / sm;
    #pragma unroll
    for (int j = 0; j < 4; j++)
        p4[j] = make_float4(v[4*j]*inv, v[4*j+1]*inv, v[4*j+2]*inv, v[4*j+3]*inv);
}

// ---------------------------------------------------------------- sampling (R5 form)
// one wave per (b, s, head); lane = (point,corner) for setup, vectorized
// 16B/lane gathers, xor-reduce, lanes 0..7 store bf16x8.
__global__ __launch_bounds__(256)
void sample_kernel(const bf16_t* __restrict__ value, const float* __restrict__ oa,
                   bf16_t* __restrict__ out) {
    int gw   = blockIdx.x * 4 + (threadIdx.x >> 6);
    int lane = threadIdx.x & 63;
    if (gw >= 2 * S_LEN * 8) return;
    int h  = gw & 7;
    int bs = gw >> 3;
    int b  = bs / S_LEN;
    int s  = bs - b * S_LEN;

    float rx, ry;
    if (s < 6400)      { int i = s;        float inv = 1.f/80.f; ry = ((i/80) + 0.5f)*inv; rx = ((i%80) + 0.5f)*inv; }
    else if (s < 8000) { int i = s - 6400; float inv = 1.f/40.f; ry = ((i/40) + 0.5f)*inv; rx = ((i%40) + 0.5f)*inv; }
    else if (s < 8400) { int i = s - 8000; float inv = 1.f/20.f; ry = ((i/20) + 0.5f)*inv; rx = ((i%20) + 0.5f)*inv; }
    else               { int i = s - 8400; float inv = 1.f/10.f; ry = ((i/10) + 0.5f)*inv; rx = ((i%10) + 0.5f)*inv; }

    const int WH[4]  = {80, 40, 20, 10};
    const int LST[4] = {0, 6400, 8000, 8400};

    // phase 1: lane = (point, corner)
    int pt = lane >> 2;
    int cn = lane & 3;
    int ll = pt >> 2;
    int W  = WH[ll];
    const float* row = oa + (size_t)bs * 384;
    float2 o2 = *(const float2*)(row + h * 32 + pt * 2);
    float  aw = row[256 + h * 16 + pt];
    float x = fmaf(rx, (float)W, o2.x) - 0.5f;
    float y = fmaf(ry, (float)W, o2.y) - 0.5f;
    float fx = floorf(x), fy = floorf(y);
    float wx = x - fx,  wy = y - fy;
    int cx = (int)fx + (cn & 1);
    int cy = (int)fy + (cn >> 1);
    float wgt = aw * ((cn & 1) ? wx : 1.f - wx) * ((cn >> 1) ? wy : 1.f - wy);
    bool valid = (cx >= 0) && (cx < W) && (cy >= 0) && (cy < W);
    if (!valid) wgt = 0.f;
    int xc = min(max(cx, 0), W - 1);
    int yc = min(max(cy, 0), W - 1);
    int addr = LST[ll] + yc * W + xc;

    // phase 2: vectorized gather
    const bf16_t* vb = value + ((size_t)b * S_LEN) * 512 + h * 64 + (lane & 7) * 8;
    int sub = lane >> 3;
    float acc[8];
    #pragma unroll
    for (int j = 0; j < 8; j++) acc[j] = 0.f;
    #pragma unroll
    for (int it = 0; it < 8; it++) {
        int pair = it * 8 + sub;
        int   a = __shfl(addr, pair, 64);
        float w = __shfl(wgt,  pair, 64);
        bf16x8 v = *(const bf16x8*)(vb + (size_t)a * 512);
        #pragma unroll
        for (int j = 0; j < 8; j++) acc[j] += w * (float)v[j];
    }

    // phase 3: reduce over pair-groups
    #pragma unroll
    for (int o = 8; o < 64; o <<= 1)
        #pragma unroll
        for (int j = 0; j < 8; j++) acc[j] += __shfl_xor(acc[j], o, 64);

    if (lane < 8) {
        bf16x8 ov;
        #pragma unroll
        for (int j = 0; j < 8; j++) ov[j] = (bf16_t)acc[j];
        *(bf16x8*)(out + (size_t)bs * 512 + h * 64 + lane * 8) = ov;
    }
}

// ---------------------------------------------------------------- LayerNorm
template<typename INA, typename INB, typename OT>
__global__ __launch_bounds__(256)
void ln_kernel(const INA* __restrict__ Xa, const INB* __restrict__ Xb,
               const float* __restrict__ g, const float* __restrict__ be,
               OT* __restrict__ out, int M) {
    int wave = threadIdx.x >> 6;
    int lane = threadIdx.x & 63;
    int row = blockIdx.x * 4 + wave;
    if (row >= M) return;
    size_t base = (size_t)row * 512;
    float v[8];
    float s = 0.f, sq = 0.f;
    #pragma unroll
    for (int p = 0; p < 2; p++) {
        int idx = p * 256 + lane * 4;
        float4 a4 = load4f(Xa + base + idx);
        float4 b4 = load4f(Xb + base + idx);
        float t0 = a4.x + b4.x, t1 = a4.y + b4.y, t2 = a4.z + b4.z, t3 = a4.w + b4.w;
        v[p*4+0] = t0; v[p*4+1] = t1; v[p*4+2] = t2; v[p*4+3] = t3;
        s  += t0 + t1 + t2 + t3;
        sq += t0*t0 + t1*t1 + t2*t2 + t3*t3;
    }
    #pragma unroll
    for (int off = 32; off > 0; off >>= 1) {
        s  += __shfl_xor(s, off, 64);
        sq += __shfl_xor(sq, off, 64);
    }
    float mean = s * (1.f / 512.f);
    float var  = sq * (1.f / 512.f) - mean * mean;
    float rstd = rsqrtf(var + 1e-5f);
    #pragma unroll
    for (int p = 0; p < 2; p++) {
        int idx = p * 256 + lane * 4;
        #pragma unroll
        for (int j = 0; j < 4; j++) {
            int col = idx + j;
            float o = (v[p*4+j] - mean) * rstd * g[col] + be[col];
            store_c(out + base + col, o);
        }
    }
}

// ---------------------------------------------------------------- launch
extern "C" void kernel_launch(void* const* d_in, const int* in_sizes, int n_in,
                              void* d_out, int out_size, void* d_ws, size_t ws_size,
                              hipStream_t stream) {
    const float* src    = (const float*)d_in[0];
    const float* pos    = (const float*)d_in[1];
    const float* w_off  = (const float*)d_in[2];
    const float* b_off  = (const float*)d_in[3];
    const float* w_attn = (const float*)d_in[4];
    const float* b_attn = (const float*)d_in[5];
    const float* w_val  = (const float*)d_in[6];
    const float* b_val  = (const float*)d_in[7];
    const float* w_out  = (const float*)d_in[8];
    const float* b_out  = (const float*)d_in[9];
    const float* ln1_g  = (const float*)d_in[10];
    const float* ln1_b  = (const float*)d_in[11];
    const float* w1     = (const float*)d_in[12];
    const float* b1     = (const float*)d_in[13];
    const float* w2     = (const float*)d_in[14];
    const float* b2     = (const float*)d_in[15];
    const float* ln2_g  = (const float*)d_in[16];
    const float* ln2_b  = (const float*)d_in[17];

    const int M = M_ROWS;
    char* ws = (char*)d_ws;
    size_t o = 0;
    auto alloc = [&](size_t bytes) { size_t r = o; o += (bytes + 255) & ~(size_t)255; return r; };

    size_t off_q       = alloc((size_t)M * 512 * 2);   // bf16
    size_t off_srcbf   = alloc((size_t)M * 512 * 2);   // bf16
    size_t off_value   = alloc((size_t)M * 512 * 2);   // bf16
    size_t off_sampled = alloc((size_t)M * 512 * 2);   // bf16
    size_t off_oa      = alloc((size_t)M * 384 * 4);   // f32 (offsets + attn logits)
    size_t off_attnout = alloc((size_t)M * 512 * 2);   // bf16
    size_t off_x       = alloc((size_t)M * 512 * 2);   // bf16
    size_t off_wtval   = alloc((size_t)512 * 512 * 2);
    size_t off_wtoa    = alloc((size_t)384 * 512 * 2);
    size_t off_wtout   = alloc((size_t)512 * 512 * 2);
    size_t off_wtw1    = alloc((size_t)1024 * 512 * 2);
    size_t off_wtw2    = alloc((size_t)512 * 1024 * 2);
    size_t off_boa     = alloc((size_t)384 * 4);

    bf16_t* q        = (bf16_t*)(ws + off_q);
    bf16_t* src_bf   = (bf16_t*)(ws + off_srcbf);
    bf16_t* value    = (bf16_t*)(ws + off_value);
    bf16_t* sampled  = (bf16_t*)(ws + off_sampled);
    float*  oa       = (float*)(ws + off_oa);
    bf16_t* attn_out = (bf16_t*)(ws + off_attnout);
    bf16_t* x        = (bf16_t*)(ws + off_x);
    bf16_t* hidden   = (bf16_t*)(ws + off_sampled);   // alias: sampled+oa dead here
    bf16_t* ffn_out  = (bf16_t*)(ws + off_attnout);   // alias: attn_out dead after ln1
    bf16_t* wt_val   = (bf16_t*)(ws + off_wtval);
    bf16_t* wt_oa    = (bf16_t*)(ws + off_wtoa);
    bf16_t* wt_out   = (bf16_t*)(ws + off_wtout);
    bf16_t* wt_w1    = (bf16_t*)(ws + off_wtw1);
    bf16_t* wt_w2    = (bf16_t*)(ws + off_wtw2);
    float*  bias_oa  = (float*)(ws + off_boa);
    float*  outp     = (float*)d_out;

    // ---- weight transposes (f32 [K][N] -> bf16 [N][K]); off+attn concat
    transpose_kernel<<<dim3(512/32,  512/32), 256, 0, stream>>>(w_val,  wt_val,  512,  512);
    transpose_kernel<<<dim3(512/32,  256/32), 256, 0, stream>>>(w_off,  wt_oa,   512,  256);
    transpose_kernel<<<dim3(512/32,  128/32), 256, 0, stream>>>(w_attn, wt_oa + (size_t)256*512, 512, 128);
    transpose_kernel<<<dim3(512/32,  512/32), 256, 0, stream>>>(w_out,  wt_out,  512,  512);
    transpose_kernel<<<dim3(512/32, 1024/32), 256, 0, stream>>>(w1,     wt_w1,   512, 1024);
    transpose_kernel<<<dim3(1024/32, 512/32), 256, 0, stream>>>(w2,     wt_w2,  1024,  512);
    prep_bias_kernel<<<1, 384, 0, stream>>>(b_off, b_attn, bias_oa);

    add_q_kernel<<<(M * 512 / 4 + 255) / 256, 256, 0, stream>>>(src, pos, q, src_bf, M * 512 / 4);

    const int MT = (M + 127) / 128;   // 133

    gemm128_kernel<bf16_t, false><<<dim3(MT, 4), 256, 0, stream>>>(src_bf, wt_val, b_val, value, M, 512, 512);
    gemm128_kernel<float,  false><<<dim3(MT, 3), 256, 0, stream>>>(q, wt_oa, bias_oa, oa, M, 384, 512);

    softmax16_kernel<<<(M * 8 + 255) / 256, 256, 0, stream>>>(oa, M * 8);

    sample_kernel<<<(M * 8) / 4, 256, 0, stream>>>(value, oa, sampled);

    gemm128_kernel<bf16_t, false><<<dim3(MT, 4), 256, 0, stream>>>(sampled, wt_out, b_out, attn_out, M, 512, 512);

    ln_kernel<float, bf16_t, bf16_t><<<(M + 3) / 4, 256, 0, stream>>>(src, attn_out, ln1_g, ln1_b, x, M);

    gemm128_kernel<bf16_t, true ><<<dim3(MT, 8), 256, 0, stream>>>(x, wt_w1, b1, hidden, M, 1024, 512);
    gemm128_kernel<bf16_t, false><<<dim3(MT, 4), 256, 0, stream>>>(hidden, wt_w2, b2, ffn_out, M, 512, 1024);

    ln_kernel<bf16_t, bf16_t, float><<<(M + 3) / 4, 256, 0, stream>>>(x, ffn_out, ln2_g, ln2_b, outp, M);
}

// Round 8
// 380.024 us; speedup vs baseline: 2.9927x; 1.1117x over previous
//
#include <hip/hip_runtime.h>

// ---------------------------------------------------------------------------
// DeformableTransformer encoder layer, MI355X (gfx950).
// R8: GEMM core switched to 32x32x16 MFMA (half the MFMA instrs, higher
// FLOP/cyc ceiling); value+oa GEMMs merged into one dispatch; all weight
// transposes + bias concat merged into one z-indexed prep kernel
// (17 -> 10 dispatches). Sample/LN/add_q unchanged (R5-proven forms).
// ---------------------------------------------------------------------------

typedef __bf16 bf16_t;
typedef __bf16 bf16x8 __attribute__((ext_vector_type(8)));
typedef __bf16 bf16x4 __attribute__((ext_vector_type(4)));
typedef float  f32x4  __attribute__((ext_vector_type(4)));
typedef float  f32x16 __attribute__((ext_vector_type(16)));

#define M_ROWS 17000   // B*S
#define S_LEN  8500

// ---------------------------------------------------------------- helpers
__device__ inline void store_c(float* p, float v)  { *p = v; }
__device__ inline void store_c(bf16_t* p, float v) { *p = (bf16_t)v; }

__device__ inline float4 load4f(const float* p)  { return *(const float4*)p; }
__device__ inline float4 load4f(const bf16_t* p) {
    bf16x4 v = *(const bf16x4*)p;
    return make_float4((float)v[0], (float)v[1], (float)v[2], (float)v[3]);
}

// ---------------------------------------------------------------- prep
// z = 0..5: transpose f32 [K][N] -> bf16 [N][K] (32x32 tiles);  z = 6: bias concat
__global__ __launch_bounds__(256)
void prep_kernel(const float* __restrict__ w_val, const float* __restrict__ w_off,
                 const float* __restrict__ w_attn, const float* __restrict__ w_out,
                 const float* __restrict__ w1, const float* __restrict__ w2,
                 const float* __restrict__ b_off, const float* __restrict__ b_attn,
                 bf16_t* __restrict__ wt_val, bf16_t* __restrict__ wt_oa,
                 bf16_t* __restrict__ wt_out, bf16_t* __restrict__ wt_w1,
                 bf16_t* __restrict__ wt_w2, float* __restrict__ bias_oa) {
    int z = blockIdx.z;
    if (z == 6) {
        if (blockIdx.x == 0 && blockIdx.y == 0) {
            for (int i = threadIdx.x; i < 384; i += 256)
                bias_oa[i] = (i < 256) ? b_off[i] : b_attn[i - 256];
        }
        return;
    }
    const float* in; bf16_t* out; int K, N;
    switch (z) {
        case 0: in = w_val;  out = wt_val;                     K = 512;  N = 512;  break;
        case 1: in = w_off;  out = wt_oa;                      K = 512;  N = 256;  break;
        case 2: in = w_attn; out = wt_oa + (size_t)256 * 512;  K = 512;  N = 128;  break;
        case 3: in = w_out;  out = wt_out;                     K = 512;  N = 512;  break;
        case 4: in = w1;     out = wt_w1;                      K = 512;  N = 1024; break;
        default: in = w2;    out = wt_w2;                      K = 1024; N = 512;  break;
    }
    int k0 = blockIdx.x * 32, n0 = blockIdx.y * 32;
    if (k0 >= K || n0 >= N) return;
    __shared__ float s[32][33];
    int tx = threadIdx.x & 31, ty = threadIdx.x >> 5;   // ty 0..7
    #pragma unroll
    for (int i = 0; i < 4; i++)
        s[ty + 8 * i][tx] = in[(size_t)(k0 + ty + 8 * i) * N + n0 + tx];
    __syncthreads();
    #pragma unroll
    for (int i = 0; i < 4; i++)
        out[(size_t)(n0 + ty + 8 * i) * K + k0 + tx] = (bf16_t)s[tx][ty + 8 * i];
}

// ---------------------------------------------------------------- q = src+pos
__global__ __launch_bounds__(256)
void add_q_kernel(const float* __restrict__ a, const float* __restrict__ b,
                  bf16_t* __restrict__ q, bf16_t* __restrict__ src_bf, int n4) {
    int i = blockIdx.x * 256 + threadIdx.x;
    if (i >= n4) return;
    float4 av = *(const float4*)(a + (size_t)i * 4);
    float4 bv = *(const float4*)(b + (size_t)i * 4);
    bf16x4 sv, ov;
    sv[0] = (bf16_t)av.x; sv[1] = (bf16_t)av.y; sv[2] = (bf16_t)av.z; sv[3] = (bf16_t)av.w;
    ov[0] = (bf16_t)(av.x + bv.x);
    ov[1] = (bf16_t)(av.y + bv.y);
    ov[2] = (bf16_t)(av.z + bv.z);
    ov[3] = (bf16_t)(av.w + bv.w);
    *(bf16x4*)(q      + (size_t)i * 4) = ov;
    *(bf16x4*)(src_bf + (size_t)i * 4) = sv;
}

// ---------------------------------------------------------------- GEMM core
// 128x128 tile, BK=32, dbuf LDS + register prefetch, 32x32x16 MFMA.
// Wave (wr,wc) computes 64x64 as 2x2 of 32x32; per iter: 8 ds_read_b128,
// 8 MFMA. A-frag: row=lane&31, k=(lane>>5)*8+j. D: col=lane&31,
// row=(reg&3)+8*(reg>>2)+4*(lane>>5)  [m74/m101 verified].
#define GEMM_CORE(A_PTR, WT_PTR, K_DIM, EPILOGUE)                                  \
    const int tid  = threadIdx.x;                                                  \
    const int wave = tid >> 6;                                                     \
    const int lane = tid & 63;                                                     \
    const int l31  = lane & 31;                                                    \
    const int lh8  = (lane >> 5) * 8;                                              \
    const int wr   = (wave >> 1) * 64;                                             \
    const int wc   = (wave & 1) * 64;                                              \
    const int row0 = blockIdx.x * 128;                                             \
    const int sr = tid >> 2;                                                       \
    const int sc = (tid & 3) * 8;                                                  \
    const bf16_t* gA0 = A_PTR  + (size_t)min(row0 + sr,      M_ROWS - 1) * K_DIM + sc; \
    const bf16_t* gA1 = A_PTR  + (size_t)min(row0 + sr + 64, M_ROWS - 1) * K_DIM + sc; \
    const bf16_t* gB0 = WT_PTR + (size_t)(col0 + sr) * K_DIM + sc;                 \
    const bf16_t* gB1 = WT_PTR + (size_t)(col0 + sr + 64) * K_DIM + sc;            \
    f32x16 acc[2][2];                                                              \
    _Pragma("unroll")                                                              \
    for (int i = 0; i < 2; i++)                                                    \
        _Pragma("unroll")                                                          \
        for (int j = 0; j < 2; j++)                                                \
            _Pragma("unroll")                                                      \
            for (int r = 0; r < 16; r++) acc[i][j][r] = 0.f;                       \
    bf16x8 pa0 = *(const bf16x8*)gA0;                                              \
    bf16x8 pa1 = *(const bf16x8*)gA1;                                              \
    bf16x8 pb0 = *(const bf16x8*)gB0;                                              \
    bf16x8 pb1 = *(const bf16x8*)gB1;                                              \
    const int nIter = K_DIM >> 5;                                                  \
    for (int it = 0; it < nIter; it++) {                                           \
        const int cur = it & 1;                                                    \
        *(bf16x8*)&As[cur][sr][sc]      = pa0;                                     \
        *(bf16x8*)&As[cur][sr + 64][sc] = pa1;                                     \
        *(bf16x8*)&Bs[cur][sr][sc]      = pb0;                                     \
        *(bf16x8*)&Bs[cur][sr + 64][sc] = pb1;                                     \
        __syncthreads();                                                           \
        if (it + 1 < nIter) {                                                      \
            int ko = (it + 1) << 5;                                                \
            pa0 = *(const bf16x8*)(gA0 + ko);                                      \
            pa1 = *(const bf16x8*)(gA1 + ko);                                      \
            pb0 = *(const bf16x8*)(gB0 + ko);                                      \
            pb1 = *(const bf16x8*)(gB1 + ko);                                      \
        }                                                                          \
        _Pragma("unroll")                                                          \
        for (int kh = 0; kh < 2; kh++) {                                           \
            bf16x8 a0 = *(const bf16x8*)&As[cur][wr + l31     ][kh * 16 + lh8];    \
            bf16x8 a1 = *(const bf16x8*)&As[cur][wr + 32 + l31][kh * 16 + lh8];    \
            bf16x8 b0 = *(const bf16x8*)&Bs[cur][wc + l31     ][kh * 16 + lh8];    \
            bf16x8 b1 = *(const bf16x8*)&Bs[cur][wc + 32 + l31][kh * 16 + lh8];    \
            acc[0][0] = __builtin_amdgcn_mfma_f32_32x32x16_bf16(a0, b0, acc[0][0], 0, 0, 0); \
            acc[0][1] = __builtin_amdgcn_mfma_f32_32x32x16_bf16(a0, b1, acc[0][1], 0, 0, 0); \
            acc[1][0] = __builtin_amdgcn_mfma_f32_32x32x16_bf16(a1, b0, acc[1][0], 0, 0, 0); \
            acc[1][1] = __builtin_amdgcn_mfma_f32_32x32x16_bf16(a1, b1, acc[1][1], 0, 0, 0); \
        }                                                                          \
    }                                                                              \
    EPILOGUE

// generic GEMM: C[M,N] = A @ Wt^T + bias, optional ReLU
template<typename OT, bool RELU>
__global__ __launch_bounds__(256)
void gemm128_kernel(const bf16_t* __restrict__ A, const bf16_t* __restrict__ Wt,
                    const float* __restrict__ bias, OT* __restrict__ Cout,
                    int N, int K) {
    __shared__ bf16_t As[2][128][40];
    __shared__ bf16_t Bs[2][128][40];
    const int col0 = blockIdx.y * 128;
    GEMM_CORE(A, Wt, K,
        {
            _Pragma("unroll")
            for (int i = 0; i < 2; i++)
                _Pragma("unroll")
                for (int j = 0; j < 2; j++) {
                    int col = col0 + wc + j * 32 + l31;
                    float bcol = bias[col];
                    _Pragma("unroll")
                    for (int reg = 0; reg < 16; reg++) {
                        int row = row0 + wr + i * 32 + (reg & 3) + 8 * (reg >> 2) + 4 * (lane >> 5);
                        if (row < M_ROWS) {
                            float v = acc[i][j][reg] + bcol;
                            if (RELU) v = fmaxf(v, 0.f);
                            store_c(Cout + (size_t)row * N + col, v);
                        }
                    }
                }
        }
    )
}

// merged value (+src_bf A) and oa (+q A) GEMM: blockIdx.y<4 -> value, else oa
__global__ __launch_bounds__(256)
void gemm_voa_kernel(const bf16_t* __restrict__ src_bf, const bf16_t* __restrict__ q,
                     const bf16_t* __restrict__ wt_val, const bf16_t* __restrict__ wt_oa,
                     const float* __restrict__ b_val, const float* __restrict__ bias_oa,
                     bf16_t* __restrict__ value, float* __restrict__ oa) {
    __shared__ bf16_t As[2][128][40];
    __shared__ bf16_t Bs[2][128][40];
    const int by    = blockIdx.y;
    const bool isV  = by < 4;
    const int col0  = (isV ? by : by - 4) * 128;
    const bf16_t* Ap  = isV ? src_bf : q;
    const bf16_t* Wp  = isV ? wt_val : wt_oa;
    const float* bp   = isV ? b_val : bias_oa;
    const int Nout    = isV ? 512 : 384;
    GEMM_CORE(Ap, Wp, 512,
        {
            _Pragma("unroll")
            for (int i = 0; i < 2; i++)
                _Pragma("unroll")
                for (int j = 0; j < 2; j++) {
                    int col = col0 + wc + j * 32 + l31;
                    float bcol = bp[col];
                    _Pragma("unroll")
                    for (int reg = 0; reg < 16; reg++) {
                        int row = row0 + wr + i * 32 + (reg & 3) + 8 * (reg >> 2) + 4 * (lane >> 5);
                        if (row < M_ROWS) {
                            float v = acc[i][j][reg] + bcol;
                            if (isV) value[(size_t)row * 512 + col] = (bf16_t)v;
                            else     oa[(size_t)row * 384 + col] = v;
                        }
                    }
                }
        }
    )
}

// ---------------------------------------------------------------- softmax16
// in-place softmax over 16 logits per (token,head) inside oa rows
__global__ __launch_bounds__(256)
void softmax16_kernel(float* __restrict__ oa, int ngroups) {
    int i = blockIdx.x * 256 + threadIdx.x;
    if (i >= ngroups) return;
    float* p = oa + (size_t)(i >> 3) * 384 + 256 + (i & 7) * 16;
    float v[16];
    float4* p4 = (float4*)p;
    #pragma unroll
    for (int j = 0; j < 4; j++) {
        float4 t = p4[j];
        v[4*j+0] = t.x; v[4*j+1] = t.y; v[4*j+2] = t.z; v[4*j+3] = t.w;
    }
    float mx = v[0];
    #pragma unroll
    for (int j = 1; j < 16; j++) mx = fmaxf(mx, v[j]);
    float sm = 0.f;
    #pragma unroll
    for (int j = 0; j < 16; j++) { v[j] = __expf(v[j] - mx); sm += v[j]; }
    float inv = 1.f / sm;
    #pragma unroll
    for (int j = 0; j < 4; j++)
        p4[j] = make_float4(v[4*j]*inv, v[4*j+1]*inv, v[4*j+2]*inv, v[4*j+3]*inv);
}

// ---------------------------------------------------------------- sampling (R5 form)
__global__ __launch_bounds__(256)
void sample_kernel(const bf16_t* __restrict__ value, const float* __restrict__ oa,
                   bf16_t* __restrict__ out) {
    int gw   = blockIdx.x * 4 + (threadIdx.x >> 6);
    int lane = threadIdx.x & 63;
    if (gw >= 2 * S_LEN * 8) return;
    int h  = gw & 7;
    int bs = gw >> 3;
    int b  = bs / S_LEN;
    int s  = bs - b * S_LEN;

    float rx, ry;
    if (s < 6400)      { int i = s;        float inv = 1.f/80.f; ry = ((i/80) + 0.5f)*inv; rx = ((i%80) + 0.5f)*inv; }
    else if (s < 8000) { int i = s - 6400; float inv = 1.f/40.f; ry = ((i/40) + 0.5f)*inv; rx = ((i%40) + 0.5f)*inv; }
    else if (s < 8400) { int i = s - 8000; float inv = 1.f/20.f; ry = ((i/20) + 0.5f)*inv; rx = ((i%20) + 0.5f)*inv; }
    else               { int i = s - 8400; float inv = 1.f/10.f; ry = ((i/10) + 0.5f)*inv; rx = ((i%10) + 0.5f)*inv; }

    const int WH[4]  = {80, 40, 20, 10};
    const int LST[4] = {0, 6400, 8000, 8400};

    int pt = lane >> 2;
    int cn = lane & 3;
    int ll = pt >> 2;
    int W  = WH[ll];
    const float* row = oa + (size_t)bs * 384;
    float2 o2 = *(const float2*)(row + h * 32 + pt * 2);
    float  aw = row[256 + h * 16 + pt];
    float x = fmaf(rx, (float)W, o2.x) - 0.5f;
    float y = fmaf(ry, (float)W, o2.y) - 0.5f;
    float fx = floorf(x), fy = floorf(y);
    float wx = x - fx,  wy = y - fy;
    int cx = (int)fx + (cn & 1);
    int cy = (int)fy + (cn >> 1);
    float wgt = aw * ((cn & 1) ? wx : 1.f - wx) * ((cn >> 1) ? wy : 1.f - wy);
    bool valid = (cx >= 0) && (cx < W) && (cy >= 0) && (cy < W);
    if (!valid) wgt = 0.f;
    int xc = min(max(cx, 0), W - 1);
    int yc = min(max(cy, 0), W - 1);
    int addr = LST[ll] + yc * W + xc;

    const bf16_t* vb = value + ((size_t)b * S_LEN) * 512 + h * 64 + (lane & 7) * 8;
    int sub = lane >> 3;
    float acc[8];
    #pragma unroll
    for (int j = 0; j < 8; j++) acc[j] = 0.f;
    #pragma unroll
    for (int it = 0; it < 8; it++) {
        int pair = it * 8 + sub;
        int   a = __shfl(addr, pair, 64);
        float w = __shfl(wgt,  pair, 64);
        bf16x8 v = *(const bf16x8*)(vb + (size_t)a * 512);
        #pragma unroll
        for (int j = 0; j < 8; j++) acc[j] += w * (float)v[j];
    }
    #pragma unroll
    for (int o = 8; o < 64; o <<= 1)
        #pragma unroll
        for (int j = 0; j < 8; j++) acc[j] += __shfl_xor(acc[j], o, 64);

    if (lane < 8) {
        bf16x8 ov;
        #pragma unroll
        for (int j = 0; j < 8; j++) ov[j] = (bf16_t)acc[j];
        *(bf16x8*)(out + (size_t)bs * 512 + h * 64 + lane * 8) = ov;
    }
}

// ---------------------------------------------------------------- LayerNorm
template<typename INA, typename INB, typename OT>
__global__ __launch_bounds__(256)
void ln_kernel(const INA* __restrict__ Xa, const INB* __restrict__ Xb,
               const float* __restrict__ g, const float* __restrict__ be,
               OT* __restrict__ out, int M) {
    int wave = threadIdx.x >> 6;
    int lane = threadIdx.x & 63;
    int row = blockIdx.x * 4 + wave;
    if (row >= M) return;
    size_t base = (size_t)row * 512;
    float v[8];
    float s = 0.f, sq = 0.f;
    #pragma unroll
    for (int p = 0; p < 2; p++) {
        int idx = p * 256 + lane * 4;
        float4 a4 = load4f(Xa + base + idx);
        float4 b4 = load4f(Xb + base + idx);
        float t0 = a4.x + b4.x, t1 = a4.y + b4.y, t2 = a4.z + b4.z, t3 = a4.w + b4.w;
        v[p*4+0] = t0; v[p*4+1] = t1; v[p*4+2] = t2; v[p*4+3] = t3;
        s  += t0 + t1 + t2 + t3;
        sq += t0*t0 + t1*t1 + t2*t2 + t3*t3;
    }
    #pragma unroll
    for (int off = 32; off > 0; off >>= 1) {
        s  += __shfl_xor(s, off, 64);
        sq += __shfl_xor(sq, off, 64);
    }
    float mean = s * (1.f / 512.f);
    float var  = sq * (1.f / 512.f) - mean * mean;
    float rstd = rsqrtf(var + 1e-5f);
    #pragma unroll
    for (int p = 0; p < 2; p++) {
        int idx = p * 256 + lane * 4;
        #pragma unroll
        for (int j = 0; j < 4; j++) {
            int col = idx + j;
            float o = (v[p*4+j] - mean) * rstd * g[col] + be[col];
            store_c(out + base + col, o);
        }
    }
}

// ---------------------------------------------------------------- launch
extern "C" void kernel_launch(void* const* d_in, const int* in_sizes, int n_in,
                              void* d_out, int out_size, void* d_ws, size_t ws_size,
                              hipStream_t stream) {
    const float* src    = (const float*)d_in[0];
    const float* pos    = (const float*)d_in[1];
    const float* w_off  = (const float*)d_in[2];
    const float* b_off  = (const float*)d_in[3];
    const float* w_attn = (const float*)d_in[4];
    const float* b_attn = (const float*)d_in[5];
    const float* w_val  = (const float*)d_in[6];
    const float* b_val  = (const float*)d_in[7];
    const float* w_out  = (const float*)d_in[8];
    const float* b_out  = (const float*)d_in[9];
    const float* ln1_g  = (const float*)d_in[10];
    const float* ln1_b  = (const float*)d_in[11];
    const float* w1     = (const float*)d_in[12];
    const float* b1     = (const float*)d_in[13];
    const float* w2     = (const float*)d_in[14];
    const float* b2     = (const float*)d_in[15];
    const float* ln2_g  = (const float*)d_in[16];
    const float* ln2_b  = (const float*)d_in[17];

    const int M = M_ROWS;
    char* ws = (char*)d_ws;
    size_t o = 0;
    auto alloc = [&](size_t bytes) { size_t r = o; o += (bytes + 255) & ~(size_t)255; return r; };

    size_t off_q       = alloc((size_t)M * 512 * 2);   // bf16
    size_t off_srcbf   = alloc((size_t)M * 512 * 2);   // bf16
    size_t off_value   = alloc((size_t)M * 512 * 2);   // bf16
    size_t off_sampled = alloc((size_t)M * 512 * 2);   // bf16
    size_t off_oa      = alloc((size_t)M * 384 * 4);   // f32
    size_t off_attnout = alloc((size_t)M * 512 * 2);   // bf16
    size_t off_x       = alloc((size_t)M * 512 * 2);   // bf16
    size_t off_wtval   = alloc((size_t)512 * 512 * 2);
    size_t off_wtoa    = alloc((size_t)384 * 512 * 2);
    size_t off_wtout   = alloc((size_t)512 * 512 * 2);
    size_t off_wtw1    = alloc((size_t)1024 * 512 * 2);
    size_t off_wtw2    = alloc((size_t)512 * 1024 * 2);
    size_t off_boa     = alloc((size_t)384 * 4);

    bf16_t* q        = (bf16_t*)(ws + off_q);
    bf16_t* src_bf   = (bf16_t*)(ws + off_srcbf);
    bf16_t* value    = (bf16_t*)(ws + off_value);
    bf16_t* sampled  = (bf16_t*)(ws + off_sampled);
    float*  oa       = (float*)(ws + off_oa);
    bf16_t* attn_out = (bf16_t*)(ws + off_attnout);
    bf16_t* x        = (bf16_t*)(ws + off_x);
    bf16_t* hidden   = (bf16_t*)(ws + off_sampled);   // alias: sampled+oa dead here
    bf16_t* ffn_out  = (bf16_t*)(ws + off_attnout);   // alias: attn_out dead after ln1
    bf16_t* wt_val   = (bf16_t*)(ws + off_wtval);
    bf16_t* wt_oa    = (bf16_t*)(ws + off_wtoa);
    bf16_t* wt_out   = (bf16_t*)(ws + off_wtout);
    bf16_t* wt_w1    = (bf16_t*)(ws + off_wtw1);
    bf16_t* wt_w2    = (bf16_t*)(ws + off_wtw2);
    float*  bias_oa  = (float*)(ws + off_boa);
    float*  outp     = (float*)d_out;

    prep_kernel<<<dim3(32, 32, 7), 256, 0, stream>>>(
        w_val, w_off, w_attn, w_out, w1, w2, b_off, b_attn,
        wt_val, wt_oa, wt_out, wt_w1, wt_w2, bias_oa);

    add_q_kernel<<<(M * 512 / 4 + 255) / 256, 256, 0, stream>>>(src, pos, q, src_bf, M * 512 / 4);

    const int MT = (M + 127) / 128;   // 133

    gemm_voa_kernel<<<dim3(MT, 7), 256, 0, stream>>>(src_bf, q, wt_val, wt_oa, b_val, bias_oa, value, oa);

    softmax16_kernel<<<(M * 8 + 255) / 256, 256, 0, stream>>>(oa, M * 8);

    sample_kernel<<<(M * 8) / 4, 256, 0, stream>>>(value, oa, sampled);

    gemm128_kernel<bf16_t, false><<<dim3(MT, 4), 256, 0, stream>>>(sampled, wt_out, b_out, attn_out, 512, 512);

    ln_kernel<float, bf16_t, bf16_t><<<(M + 3) / 4, 256, 0, stream>>>(src, attn_out, ln1_g, ln1_b, x, M);

    gemm128_kernel<bf16_t, true ><<<dim3(MT, 8), 256, 0, stream>>>(x, wt_w1, b1, hidden, 1024, 512);
    gemm128_kernel<bf16_t, false><<<dim3(MT, 4), 256, 0, stream>>>(hidden, wt_w2, b2, ffn_out, 512, 1024);

    ln_kernel<bf16_t, bf16_t, float><<<(M + 3) / 4, 256, 0, stream>>>(x, ffn_out, ln2_g, ln2_b, outp, M);
}